// Round 1
// baseline (1626.211 us; speedup 1.0000x reference)
//
#include <hip/hip_runtime.h>

typedef _Float16 f16;
typedef _Float16 f16x2 __attribute__((ext_vector_type(2)));

#define Hh 512
#define SS 256
#define TT 256
#define VTOT 32000
#define VTILE 64
#define NB 4

__device__ inline float fdot2(unsigned int a, unsigned int b, float c) {
#if __has_builtin(__builtin_amdgcn_fdot2)
    return __builtin_amdgcn_fdot2(__builtin_bit_cast(f16x2, a),
                                  __builtin_bit_cast(f16x2, b), c, false);
#else
    f16x2 x = __builtin_bit_cast(f16x2, a), y = __builtin_bit_cast(f16x2, b);
    return c + (float)x[0] * (float)y[0] + (float)x[1] * (float)y[1];
#endif
}

__device__ inline float block_sum(float v, float* red) {
#pragma unroll
    for (int o = 1; o < 64; o <<= 1) v += __shfl_xor(v, o);
    if ((threadIdx.x & 63) == 0) red[threadIdx.x >> 6] = v;
    __syncthreads();
    v = red[0] + red[1] + red[2] + red[3];
    __syncthreads();
    return v;
}

__device__ inline float block_max(float v, float* red) {
#pragma unroll
    for (int o = 1; o < 64; o <<= 1) v = fmaxf(v, __shfl_xor(v, o));
    if ((threadIdx.x & 63) == 0) red[threadIdx.x >> 6] = v;
    __syncthreads();
    v = fmaxf(fmaxf(red[0], red[1]), fmaxf(red[2], red[3]));
    __syncthreads();
    return v;
}

// ---- embeddings: gather + L2-normalize. grid 512 (256 src + 256 tgt), 256 thr
__global__ void __launch_bounds__(256) k_emb(const int* __restrict__ src,
                                             const int* __restrict__ tgt,
                                             const float* __restrict__ encW,
                                             const float* __restrict__ decW,
                                             float* __restrict__ emb) {
    const int c = blockIdx.x >> 8, t = blockIdx.x & 255, tid = threadIdx.x;
    const int idx = c ? tgt[t] : src[t];
    const float* row = (c ? decW : encW) + (size_t)idx * Hh;
    float2 v = ((const float2*)row)[tid];
    __shared__ float red[4];
    float tot = block_sum(v.x * v.x + v.y * v.y, red);
    float inv = 1.f / fmaxf(sqrtf(tot), 1e-12f);
    float* orow = emb + ((size_t)c * TT + t) * Hh;
    float2 o;
    o.x = v.x * inv;
    o.y = v.y * inv;
    ((float2*)orow)[tid] = o;
}

// ---- init h0 slots. grid 2, 256 thr
__global__ void k_init(const float* __restrict__ eh0, const float* __restrict__ dh0,
                       f16* __restrict__ hx, float* __restrict__ h_seq,
                       float* __restrict__ Hd) {
    const int c = blockIdx.x, tid = threadIdx.x;
    const float* h0 = c ? dh0 : eh0;
    float2 v = ((const float2*)h0)[tid];
    f16* dst = hx + (size_t)c * 257 * Hh;
    dst[2 * tid] = (f16)v.x;
    dst[2 * tid + 1] = (f16)v.y;
    if (c == 0)
        ((float2*)h_seq)[tid] = v;
    else
        ((float2*)Hd)[tid] = v;
}

// ---- convert both W_hh to f16. grid 256, 256 thr, 8 elems each
__global__ void k_cvt(const float* __restrict__ enc, const float* __restrict__ dec,
                      f16* __restrict__ dst) {
    size_t i = ((size_t)blockIdx.x * 256 + threadIdx.x) * 8;
    const float* s = (i < (size_t)Hh * Hh) ? enc + i : dec + (i - (size_t)Hh * Hh);
    float4 v0 = ((const float4*)s)[0];
    float4 v1 = ((const float4*)s)[1];
    f16x2 p0 = {(f16)v0.x, (f16)v0.y};
    f16x2 p1 = {(f16)v0.z, (f16)v0.w};
    f16x2 p2 = {(f16)v1.x, (f16)v1.y};
    f16x2 p3 = {(f16)v1.z, (f16)v1.w};
    uint4 u;
    u.x = __builtin_bit_cast(unsigned, p0);
    u.y = __builtin_bit_cast(unsigned, p1);
    u.z = __builtin_bit_cast(unsigned, p2);
    u.w = __builtin_bit_cast(unsigned, p3);
    *((uint4*)(dst + i)) = u;
}

// ---- P = emb @ W_hi^T + b. grid (256, 2), 256 thr
__global__ void __launch_bounds__(256) k_proj(const float* __restrict__ emb,
                                              const float* __restrict__ eWhi,
                                              const float* __restrict__ eb,
                                              const float* __restrict__ dWhi,
                                              const float* __restrict__ db,
                                              float* __restrict__ P) {
    const int c = blockIdx.y, t = blockIdx.x, tid = threadIdx.x;
    const float* Wv = c ? dWhi : eWhi;
    const float* b = c ? db : eb;
    __shared__ float e[Hh];
    const float* erow = emb + ((size_t)c * TT + t) * Hh;
    ((float2*)e)[tid] = ((const float2*)erow)[tid];
    __syncthreads();
    float* out = P + ((size_t)c * TT + t) * Hh;
#pragma unroll
    for (int rep = 0; rep < 2; ++rep) {
        int i = tid + rep * 256;
        const float4* wr = (const float4*)(Wv + (size_t)i * Hh);
        float a = 0.f;
        for (int j = 0; j < Hh / 4; ++j) {
            float4 w4 = wr[j];
            a += w4.x * e[4 * j] + w4.y * e[4 * j + 1] + w4.z * e[4 * j + 2] +
                 w4.w * e[4 * j + 3];
        }
        out[i] = a + b[i];
    }
}

// ---- sequential RNN chains. grid 8 (2 chains x 4 blocks), 256 thr.
// W slab (128 rows f16) register-resident; h exchanged via slot-rotated global
// buffer + agent-scope flags.
__global__ void __launch_bounds__(256, 1) k_chain(const f16* __restrict__ w16,
                                                  const float* __restrict__ P,
                                                  f16* __restrict__ hx,
                                                  float* __restrict__ h_seq,
                                                  float* __restrict__ Hd,
                                                  int* __restrict__ flags) {
    const int chain = blockIdx.x >> 2, blk = blockIdx.x & 3, tid = threadIdx.x;
    const int ol = tid >> 1, kh = tid & 1;
    const int o = blk * 128 + ol;
    const uint4* wsrc =
        (const uint4*)(w16 + ((size_t)chain * Hh + o) * Hh + (size_t)kh * 256);
    uint4 wreg[32];
#pragma unroll
    for (int i = 0; i < 32; ++i) wreg[i] = wsrc[i];
    f16* hxc = hx + (size_t)chain * 257 * Hh;
    const float* Pc = P + (size_t)chain * TT * Hh;
    int* flg = flags + chain * NB;

    for (int step = 0; step < 256; ++step) {
        if (step > 0) {
            if (tid < NB) {
                int g = 0;
                while (__hip_atomic_load(flg + tid, __ATOMIC_ACQUIRE,
                                         __HIP_MEMORY_SCOPE_AGENT) < step) {
                    __builtin_amdgcn_s_sleep(1);
                    if (++g > (1 << 24)) break;  // safety: fail loud, not hang
                }
            }
            __syncthreads();
        }
        const uint4* hsrc = (const uint4*)(hxc + (size_t)step * Hh + (size_t)kh * 256);
        float a0 = 0.f, a1 = 0.f, a2 = 0.f, a3 = 0.f;
#pragma unroll
        for (int i = 0; i < 32; ++i) {
            uint4 hv = hsrc[i];
            uint4 wv = wreg[i];
            a0 = fdot2(wv.x, hv.x, a0);
            a1 = fdot2(wv.y, hv.y, a1);
            a2 = fdot2(wv.z, hv.z, a2);
            a3 = fdot2(wv.w, hv.w, a3);
        }
        float acc = (a0 + a1) + (a2 + a3);
        acc += __shfl_xor(acc, 1);
        if (kh == 0) {
            float hv = tanhf(acc + Pc[(size_t)step * Hh + o]);
            hxc[(size_t)(step + 1) * Hh + o] = (f16)hv;
            if (chain == 0)
                h_seq[(size_t)(step + 1) * Hh + o] = hv;
            else if (step < 255)
                Hd[(size_t)(step + 1) * Hh + o] = hv;
        }
        __syncthreads();
        if (tid == 0) {
            __threadfence();
            __hip_atomic_store(flg + blk, step + 1, __ATOMIC_RELEASE,
                               __HIP_MEMORY_SCOPE_AGENT);
        }
    }
}

// ---- attention + z for all t. grid 256, 256 thr
__global__ void __launch_bounds__(256) k_attn(const float* __restrict__ h_seq,
                                              const float* __restrict__ Hd,
                                              const float* __restrict__ tnhW,
                                              const float* __restrict__ tnhb,
                                              float* __restrict__ Z) {
    const int t = blockIdx.x, tid = threadIdx.x;
    __shared__ float h[Hh];
    __shared__ float c[Hh];
    __shared__ float w[257];
    __shared__ float red[4];
    ((float2*)h)[tid] = ((const float2*)(Hd + (size_t)t * Hh))[tid];
    __syncthreads();
    float sc0, sc1 = -3.0e38f;
    {
        const float4* row = (const float4*)(h_seq + (size_t)tid * Hh);
        float a = 0.f;
        for (int j = 0; j < Hh / 4; ++j) {
            float4 v = row[j];
            a += v.x * h[4 * j] + v.y * h[4 * j + 1] + v.z * h[4 * j + 2] +
                 v.w * h[4 * j + 3];
        }
        sc0 = a;
    }
    if (tid == 0) {
        const float4* row = (const float4*)(h_seq + (size_t)256 * Hh);
        float a = 0.f;
        for (int j = 0; j < Hh / 4; ++j) {
            float4 v = row[j];
            a += v.x * h[4 * j] + v.y * h[4 * j + 1] + v.z * h[4 * j + 2] +
                 v.w * h[4 * j + 3];
        }
        sc1 = a;
    }
    float m = block_max(fmaxf(sc0, sc1), red);
    float e0 = expf(sc0 - m);
    float e1 = (tid == 0) ? expf(sc1 - m) : 0.f;
    float tot = block_sum(e0 + e1, red);
    float inv = 1.f / tot;
    w[tid] = e0 * inv;
    if (tid == 0) w[256] = e1 * inv;
    __syncthreads();
#pragma unroll
    for (int r = 0; r < 2; ++r) {
        int j = tid + r * 256;
        float a = 0.f;
        for (int s = 0; s < 257; ++s) a += w[s] * h_seq[(size_t)s * Hh + j];
        c[j] = a;
    }
    __syncthreads();
#pragma unroll
    for (int r = 0; r < 2; ++r) {
        int i = tid + r * 256;
        const float4* row = (const float4*)(tnhW + (size_t)i * (2 * Hh));
        float a = 0.f;
        for (int j = 0; j < Hh / 4; ++j) {
            float4 v = row[j];
            a += v.x * c[4 * j] + v.y * c[4 * j + 1] + v.z * c[4 * j + 2] +
                 v.w * c[4 * j + 3];
        }
        for (int j = 0; j < Hh / 4; ++j) {
            float4 v = row[Hh / 4 + j];
            a += v.x * h[4 * j] + v.y * h[4 * j + 1] + v.z * h[4 * j + 2] +
                 v.w * h[4 * j + 3];
        }
        Z[(size_t)t * Hh + i] = tanhf(a + tnhb[i]);
    }
}

// ---- logits GEMM + fused partial logsumexp. grid 500 (VTILE=64 rows each), 256 thr
__global__ void __launch_bounds__(256, 2) k_logits(const float* __restrict__ Z,
                                                   const float* __restrict__ outW,
                                                   const int* __restrict__ tgt,
                                                   float* __restrict__ denom,
                                                   float* __restrict__ ltgt) {
    const int v0 = blockIdx.x * VTILE;
    const int t = threadIdx.x;  // one t-row per thread
    __shared__ float4 Wl[VTILE][16];
    float acc[VTILE];
#pragma unroll
    for (int v = 0; v < VTILE; ++v) acc[v] = 0.f;

    for (int k0 = 0; k0 < Hh; k0 += 64) {
        __syncthreads();
        for (int idx = t; idx < VTILE * 16; idx += 256) {
            int vv = idx >> 4, c4 = idx & 15;
            Wl[vv][c4] = ((const float4*)(outW + (size_t)(v0 + vv) * Hh + k0))[c4];
        }
        float4 zr[16];
        const float4* zp = (const float4*)(Z + (size_t)t * Hh + k0);
#pragma unroll
        for (int j = 0; j < 16; ++j) zr[j] = zp[j];
        __syncthreads();
#pragma unroll
        for (int v = 0; v < VTILE; ++v) {
            float a = acc[v];
#pragma unroll
            for (int j = 0; j < 16; ++j) {
                float4 wv = Wl[v][j];
                a += wv.x * zr[j].x + wv.y * zr[j].y + wv.z * zr[j].z + wv.w * zr[j].w;
            }
            acc[v] = a;
        }
    }
    float se = 0.f;
#pragma unroll
    for (int v = 0; v < VTILE; ++v) se += expf(acc[v]);
    atomicAdd(&denom[t], se);
    int rel = tgt[t] - v0;
    if (rel >= 0 && rel < VTILE) {
        float val = 0.f;
#pragma unroll
        for (int v = 0; v < VTILE; ++v) val = (v == rel) ? acc[v] : val;
        ltgt[t] = val;
    }
}

// ---- final: nll_t = log(denom_t) - logit_tgt_t; mean. grid 1, 256 thr
__global__ void k_final(const float* __restrict__ denom, const float* __restrict__ ltgt,
                        float* __restrict__ out) {
    const int t = threadIdx.x;
    float nll = logf(denom[t]) - ltgt[t];
    __shared__ float red[4];
    float v = nll;
#pragma unroll
    for (int o = 1; o < 64; o <<= 1) v += __shfl_xor(v, o);
    if ((t & 63) == 0) red[t >> 6] = v;
    __syncthreads();
    if (t == 0) out[0] = (red[0] + red[1] + red[2] + red[3]) * (1.f / 256.f);
}

extern "C" void kernel_launch(void* const* d_in, const int* in_sizes, int n_in,
                              void* d_out, int out_size, void* d_ws, size_t ws_size,
                              hipStream_t stream) {
    (void)in_sizes; (void)n_in; (void)out_size; (void)ws_size;
    const int* src = (const int*)d_in[0];
    const int* tgt = (const int*)d_in[1];
    const float* enc_emb = (const float*)d_in[2];
    const float* enc_h0 = (const float*)d_in[3];
    const float* enc_Whi = (const float*)d_in[4];
    const float* enc_Whh = (const float*)d_in[5];
    const float* enc_b = (const float*)d_in[6];
    const float* dec_emb = (const float*)d_in[7];
    const float* dec_h0 = (const float*)d_in[8];
    const float* dec_Whi = (const float*)d_in[9];
    const float* dec_Whh = (const float*)d_in[10];
    const float* dec_b = (const float*)d_in[11];
    const float* tnhW = (const float*)d_in[12];
    const float* tnhb = (const float*)d_in[13];
    const float* outW = (const float*)d_in[14];
    float* out = (float*)d_out;
    char* ws = (char*)d_ws;

    int* flags = (int*)ws;                    // 8 ints
    float* denom = (float*)(ws + 64);         // 256 f32
    float* ltgt = (float*)(ws + 64 + 1024);   // 256 f32
    size_t off = 4096;
    float* emb = (float*)(ws + off);  off += (size_t)2 * TT * Hh * 4;
    float* P = (float*)(ws + off);    off += (size_t)2 * TT * Hh * 4;
    float* h_seq = (float*)(ws + off); off += (size_t)257 * Hh * 4;
    float* Hd = (float*)(ws + off);   off += (size_t)256 * Hh * 4;
    f16* hx = (f16*)(ws + off);       off += (size_t)2 * 257 * Hh * 2;
    f16* w16 = (f16*)(ws + off);      off += (size_t)2 * Hh * Hh * 2;
    float* Zb = (float*)(ws + off);   off += (size_t)TT * Hh * 4;

    hipMemsetAsync(ws, 0, 64 + 2048, stream);  // flags + denom + ltgt
    k_emb<<<512, 256, 0, stream>>>(src, tgt, enc_emb, dec_emb, emb);
    k_init<<<2, 256, 0, stream>>>(enc_h0, dec_h0, hx, h_seq, Hd);
    k_cvt<<<256, 256, 0, stream>>>(enc_Whh, dec_Whh, w16);
    k_proj<<<dim3(256, 2), 256, 0, stream>>>(emb, enc_Whi, enc_b, dec_Whi, dec_b, P);
    k_chain<<<8, 256, 0, stream>>>(w16, P, hx, h_seq, Hd, flags);
    k_attn<<<256, 256, 0, stream>>>(h_seq, Hd, tnhW, tnhb, Zb);
    k_logits<<<VTOT / VTILE, 256, 0, stream>>>(Zb, outW, tgt, denom, ltgt);
    k_final<<<1, 256, 0, stream>>>(denom, ltgt, out);
}

// Round 2
// 858.550 us; speedup vs baseline: 1.8941x; 1.8941x over previous
//
#include <hip/hip_runtime.h>

typedef _Float16 f16;
typedef _Float16 f16x2 __attribute__((ext_vector_type(2)));

#define Hh 512
#define SS 256
#define TT 256
#define VTOT 32000
#define VTILE 64

// W_hh column split per thread-row: registers / LDS / L2-streamed
#define REGC 384
#define LDSC 56
#define L2C 72
#define NLDS (LDSC / 8)  // 7 chunks of 8 f16
#define NL2 (L2C / 8)    // 9 chunks of 8 f16

__device__ inline float fdot2(unsigned int a, unsigned int b, float c) {
#if __has_builtin(__builtin_amdgcn_fdot2)
    return __builtin_amdgcn_fdot2(__builtin_bit_cast(f16x2, a),
                                  __builtin_bit_cast(f16x2, b), c, false);
#else
    f16x2 x = __builtin_bit_cast(f16x2, a), y = __builtin_bit_cast(f16x2, b);
    return c + (float)x[0] * (float)y[0] + (float)x[1] * (float)y[1];
#endif
}

__device__ inline float block_sum(float v, float* red) {
#pragma unroll
    for (int o = 1; o < 64; o <<= 1) v += __shfl_xor(v, o);
    if ((threadIdx.x & 63) == 0) red[threadIdx.x >> 6] = v;
    __syncthreads();
    v = red[0] + red[1] + red[2] + red[3];
    __syncthreads();
    return v;
}

__device__ inline float block_max(float v, float* red) {
#pragma unroll
    for (int o = 1; o < 64; o <<= 1) v = fmaxf(v, __shfl_xor(v, o));
    if ((threadIdx.x & 63) == 0) red[threadIdx.x >> 6] = v;
    __syncthreads();
    v = fmaxf(fmaxf(red[0], red[1]), fmaxf(red[2], red[3]));
    __syncthreads();
    return v;
}

// ---- embeddings: gather + L2-normalize. grid 512 (256 src + 256 tgt), 256 thr
__global__ void __launch_bounds__(256) k_emb(const int* __restrict__ src,
                                             const int* __restrict__ tgt,
                                             const float* __restrict__ encW,
                                             const float* __restrict__ decW,
                                             float* __restrict__ emb) {
    const int c = blockIdx.x >> 8, t = blockIdx.x & 255, tid = threadIdx.x;
    const int idx = c ? tgt[t] : src[t];
    const float* row = (c ? decW : encW) + (size_t)idx * Hh;
    float2 v = ((const float2*)row)[tid];
    __shared__ float red[4];
    float tot = block_sum(v.x * v.x + v.y * v.y, red);
    float inv = 1.f / fmaxf(sqrtf(tot), 1e-12f);
    float* orow = emb + ((size_t)c * TT + t) * Hh;
    float2 o;
    o.x = v.x * inv;
    o.y = v.y * inv;
    ((float2*)orow)[tid] = o;
}

// ---- init h_seq[0], Hd[0]. grid 2, 256 thr
__global__ void k_init(const float* __restrict__ eh0, const float* __restrict__ dh0,
                       float* __restrict__ h_seq, float* __restrict__ Hd) {
    const int c = blockIdx.x, tid = threadIdx.x;
    const float* h0 = c ? dh0 : eh0;
    float2 v = ((const float2*)h0)[tid];
    if (c == 0)
        ((float2*)h_seq)[tid] = v;
    else
        ((float2*)Hd)[tid] = v;
}

// ---- rearrange+convert W_hh to f16 in three layouts. grid 1024 (c,row), 64 thr
// Wreg: [2][512][REGC]          (row-contiguous, per-thread one-time load)
// WldsG:[2][NLDS][512][8]       (staged to LDS; [chunk][tid][16B])
// WL2:  [2][NL2][512][8]        (per-step coalesced L2 stream)
__global__ void k_cvt(const float* __restrict__ enc, const float* __restrict__ dec,
                      f16* __restrict__ Wreg, f16* __restrict__ WldsG,
                      f16* __restrict__ WL2) {
    const int c = blockIdx.x >> 9, r = blockIdx.x & 511, col0 = threadIdx.x * 8;
    const float* s = (c ? dec : enc) + (size_t)r * Hh + col0;
    float4 v0 = ((const float4*)s)[0];
    float4 v1 = ((const float4*)s)[1];
    f16x2 p0 = {(f16)v0.x, (f16)v0.y};
    f16x2 p1 = {(f16)v0.z, (f16)v0.w};
    f16x2 p2 = {(f16)v1.x, (f16)v1.y};
    f16x2 p3 = {(f16)v1.z, (f16)v1.w};
    uint4 u;
    u.x = __builtin_bit_cast(unsigned, p0);
    u.y = __builtin_bit_cast(unsigned, p1);
    u.z = __builtin_bit_cast(unsigned, p2);
    u.w = __builtin_bit_cast(unsigned, p3);
    f16* dst;
    if (col0 < REGC) {
        dst = Wreg + ((size_t)(c * 512 + r) * REGC + col0);
    } else if (col0 < REGC + LDSC) {
        int jj = (col0 - REGC) >> 3;
        dst = WldsG + ((size_t)(c * NLDS + jj) * 512 + r) * 8;
    } else {
        int jj = (col0 - REGC - LDSC) >> 3;
        dst = WL2 + ((size_t)(c * NL2 + jj) * 512 + r) * 8;
    }
    *((uint4*)dst) = u;
}

// ---- P = emb @ W_hi^T + b. grid (256, 2), 256 thr
__global__ void __launch_bounds__(256) k_proj(const float* __restrict__ emb,
                                              const float* __restrict__ eWhi,
                                              const float* __restrict__ eb,
                                              const float* __restrict__ dWhi,
                                              const float* __restrict__ db,
                                              float* __restrict__ P) {
    const int c = blockIdx.y, t = blockIdx.x, tid = threadIdx.x;
    const float* Wv = c ? dWhi : eWhi;
    const float* b = c ? db : eb;
    __shared__ float e[Hh];
    const float* erow = emb + ((size_t)c * TT + t) * Hh;
    ((float2*)e)[tid] = ((const float2*)erow)[tid];
    __syncthreads();
    float* out = P + ((size_t)c * TT + t) * Hh;
#pragma unroll
    for (int rep = 0; rep < 2; ++rep) {
        int i = tid + rep * 256;
        const float4* wr = (const float4*)(Wv + (size_t)i * Hh);
        float a = 0.f;
        for (int j = 0; j < Hh / 4; ++j) {
            float4 w4 = wr[j];
            a += w4.x * e[4 * j] + w4.y * e[4 * j + 1] + w4.z * e[4 * j + 2] +
                 w4.w * e[4 * j + 3];
        }
        out[i] = a + b[i];
    }
}

// ---- sequential RNN chains. grid 2 (chain), 512 thr, SINGLE workgroup per
// chain: h exchange via LDS + __syncthreads only (no cross-WG coherence).
// Thread t owns output row t: 384 cols in regs, 56 in LDS, 72 streamed from L2.
__global__ void __launch_bounds__(512, 2) k_chain(
    const f16* __restrict__ Wreg, const f16* __restrict__ WldsG,
    const f16* __restrict__ WL2, const float* __restrict__ P,
    const float* __restrict__ eh0, const float* __restrict__ dh0,
    float* __restrict__ h_seq, float* __restrict__ Hd) {
    const int c = blockIdx.x, t = threadIdx.x;
    __shared__ __align__(16) f16 hbuf[2][Hh];
    __shared__ __align__(16) f16 wl[NLDS][512][8];

    // stage LDS W chunks (coalesced 16B/lane)
#pragma unroll
    for (int jj = 0; jj < NLDS; ++jj) {
        *((uint4*)&wl[jj][t][0]) =
            *((const uint4*)(WldsG + ((size_t)(c * NLDS + jj) * 512 + t) * 8));
    }
    // one-time register W load (768B per thread)
    uint4 wreg[REGC / 8];
    {
        const uint4* wsrc = (const uint4*)(Wreg + (size_t)(c * 512 + t) * REGC);
#pragma unroll
        for (int k = 0; k < REGC / 8; ++k) wreg[k] = wsrc[k];
    }
    // h0
    hbuf[0][t] = (f16)((c ? dh0 : eh0)[t]);
    __syncthreads();

    const float* Pc = P + (size_t)c * TT * Hh;
    float pv = Pc[t];  // P for step 0

    for (int step = 0; step < 256; ++step) {
        const int cur = step & 1;
        // issue L2-resident W stream early (no dependence on h)
        uint4 wb[NL2];
#pragma unroll
        for (int jj = 0; jj < NL2; ++jj) {
            wb[jj] = *((const uint4*)(WL2 + ((size_t)(c * NL2 + jj) * 512 + t) * 8));
        }
        float a0 = 0.f, a1 = 0.f, a2 = 0.f, a3 = 0.f;
        // register part: cols 0..REGC-1 (h reads are wave-broadcast)
#pragma unroll
        for (int k = 0; k < REGC / 8; ++k) {
            uint4 hv = *((const uint4*)&hbuf[cur][k * 8]);
            uint4 wv = wreg[k];
            a0 = fdot2(wv.x, hv.x, a0);
            a1 = fdot2(wv.y, hv.y, a1);
            a2 = fdot2(wv.z, hv.z, a2);
            a3 = fdot2(wv.w, hv.w, a3);
        }
        // LDS part: cols REGC..REGC+LDSC-1
#pragma unroll
        for (int jj = 0; jj < NLDS; ++jj) {
            uint4 hv = *((const uint4*)&hbuf[cur][REGC + jj * 8]);
            uint4 wv = *((const uint4*)&wl[jj][t][0]);
            a0 = fdot2(wv.x, hv.x, a0);
            a1 = fdot2(wv.y, hv.y, a1);
            a2 = fdot2(wv.z, hv.z, a2);
            a3 = fdot2(wv.w, hv.w, a3);
        }
        // L2-streamed part: cols REGC+LDSC..511
#pragma unroll
        for (int jj = 0; jj < NL2; ++jj) {
            uint4 hv = *((const uint4*)&hbuf[cur][REGC + LDSC + jj * 8]);
            uint4 wv = wb[jj];
            a0 = fdot2(wv.x, hv.x, a0);
            a1 = fdot2(wv.y, hv.y, a1);
            a2 = fdot2(wv.z, hv.z, a2);
            a3 = fdot2(wv.w, hv.w, a3);
        }
        float pre = (a0 + a1) + (a2 + a3) + pv;
        float hnew = tanhf(pre);
        if (step < 255) pv = Pc[(size_t)(step + 1) * Hh + t];  // prefetch next P
        hbuf[cur ^ 1][t] = (f16)hnew;
        if (c == 0)
            h_seq[(size_t)(step + 1) * Hh + t] = hnew;
        else if (step < 255)
            Hd[(size_t)(step + 1) * Hh + t] = hnew;
        __syncthreads();
    }
}

// ---- attention + z for all t. grid 256, 256 thr
__global__ void __launch_bounds__(256) k_attn(const float* __restrict__ h_seq,
                                              const float* __restrict__ Hd,
                                              const float* __restrict__ tnhW,
                                              const float* __restrict__ tnhb,
                                              float* __restrict__ Z) {
    const int t = blockIdx.x, tid = threadIdx.x;
    __shared__ float h[Hh];
    __shared__ float c[Hh];
    __shared__ float w[257];
    __shared__ float red[4];
    ((float2*)h)[tid] = ((const float2*)(Hd + (size_t)t * Hh))[tid];
    __syncthreads();
    float sc0, sc1 = -3.0e38f;
    {
        const float4* row = (const float4*)(h_seq + (size_t)tid * Hh);
        float a = 0.f;
        for (int j = 0; j < Hh / 4; ++j) {
            float4 v = row[j];
            a += v.x * h[4 * j] + v.y * h[4 * j + 1] + v.z * h[4 * j + 2] +
                 v.w * h[4 * j + 3];
        }
        sc0 = a;
    }
    if (tid == 0) {
        const float4* row = (const float4*)(h_seq + (size_t)256 * Hh);
        float a = 0.f;
        for (int j = 0; j < Hh / 4; ++j) {
            float4 v = row[j];
            a += v.x * h[4 * j] + v.y * h[4 * j + 1] + v.z * h[4 * j + 2] +
                 v.w * h[4 * j + 3];
        }
        sc1 = a;
    }
    float m = block_max(fmaxf(sc0, sc1), red);
    float e0 = expf(sc0 - m);
    float e1 = (tid == 0) ? expf(sc1 - m) : 0.f;
    float tot = block_sum(e0 + e1, red);
    float inv = 1.f / tot;
    w[tid] = e0 * inv;
    if (tid == 0) w[256] = e1 * inv;
    __syncthreads();
#pragma unroll
    for (int r = 0; r < 2; ++r) {
        int j = tid + r * 256;
        float a = 0.f;
        for (int s = 0; s < 257; ++s) a += w[s] * h_seq[(size_t)s * Hh + j];
        c[j] = a;
    }
    __syncthreads();
#pragma unroll
    for (int r = 0; r < 2; ++r) {
        int i = tid + r * 256;
        const float4* row = (const float4*)(tnhW + (size_t)i * (2 * Hh));
        float a = 0.f;
        for (int j = 0; j < Hh / 4; ++j) {
            float4 v = row[j];
            a += v.x * c[4 * j] + v.y * c[4 * j + 1] + v.z * c[4 * j + 2] +
                 v.w * c[4 * j + 3];
        }
        for (int j = 0; j < Hh / 4; ++j) {
            float4 v = row[Hh / 4 + j];
            a += v.x * h[4 * j] + v.y * h[4 * j + 1] + v.z * h[4 * j + 2] +
                 v.w * h[4 * j + 3];
        }
        Z[(size_t)t * Hh + i] = tanhf(a + tnhb[i]);
    }
}

// ---- logits GEMM + fused partial logsumexp. grid 500 (VTILE=64 rows each), 256 thr
__global__ void __launch_bounds__(256, 2) k_logits(const float* __restrict__ Z,
                                                   const float* __restrict__ outW,
                                                   const int* __restrict__ tgt,
                                                   float* __restrict__ denom,
                                                   float* __restrict__ ltgt) {
    const int v0 = blockIdx.x * VTILE;
    const int t = threadIdx.x;  // one t-row per thread
    __shared__ float4 Wl[VTILE][16];
    float acc[VTILE];
#pragma unroll
    for (int v = 0; v < VTILE; ++v) acc[v] = 0.f;

    for (int k0 = 0; k0 < Hh; k0 += 64) {
        __syncthreads();
        for (int idx = t; idx < VTILE * 16; idx += 256) {
            int vv = idx >> 4, c4 = idx & 15;
            Wl[vv][c4] = ((const float4*)(outW + (size_t)(v0 + vv) * Hh + k0))[c4];
        }
        float4 zr[16];
        const float4* zp = (const float4*)(Z + (size_t)t * Hh + k0);
#pragma unroll
        for (int j = 0; j < 16; ++j) zr[j] = zp[j];
        __syncthreads();
#pragma unroll
        for (int v = 0; v < VTILE; ++v) {
            float a = acc[v];
#pragma unroll
            for (int j = 0; j < 16; ++j) {
                float4 wv = Wl[v][j];
                a += wv.x * zr[j].x + wv.y * zr[j].y + wv.z * zr[j].z + wv.w * zr[j].w;
            }
            acc[v] = a;
        }
    }
    float se = 0.f;
#pragma unroll
    for (int v = 0; v < VTILE; ++v) se += expf(acc[v]);
    atomicAdd(&denom[t], se);
    int rel = tgt[t] - v0;
    if (rel >= 0 && rel < VTILE) {
        float val = 0.f;
#pragma unroll
        for (int v = 0; v < VTILE; ++v) val = (v == rel) ? acc[v] : val;
        ltgt[t] = val;
    }
}

// ---- final: nll_t = log(denom_t) - logit_tgt_t; mean. grid 1, 256 thr
__global__ void k_final(const float* __restrict__ denom, const float* __restrict__ ltgt,
                        float* __restrict__ out) {
    const int t = threadIdx.x;
    float nll = logf(denom[t]) - ltgt[t];
    __shared__ float red[4];
    float v = nll;
#pragma unroll
    for (int o = 1; o < 64; o <<= 1) v += __shfl_xor(v, o);
    if ((t & 63) == 0) red[t >> 6] = v;
    __syncthreads();
    if (t == 0) out[0] = (red[0] + red[1] + red[2] + red[3]) * (1.f / 256.f);
}

extern "C" void kernel_launch(void* const* d_in, const int* in_sizes, int n_in,
                              void* d_out, int out_size, void* d_ws, size_t ws_size,
                              hipStream_t stream) {
    (void)in_sizes; (void)n_in; (void)out_size; (void)ws_size;
    const int* src = (const int*)d_in[0];
    const int* tgt = (const int*)d_in[1];
    const float* enc_emb = (const float*)d_in[2];
    const float* enc_h0 = (const float*)d_in[3];
    const float* enc_Whi = (const float*)d_in[4];
    const float* enc_Whh = (const float*)d_in[5];
    const float* enc_b = (const float*)d_in[6];
    const float* dec_emb = (const float*)d_in[7];
    const float* dec_h0 = (const float*)d_in[8];
    const float* dec_Whi = (const float*)d_in[9];
    const float* dec_Whh = (const float*)d_in[10];
    const float* dec_b = (const float*)d_in[11];
    const float* tnhW = (const float*)d_in[12];
    const float* tnhb = (const float*)d_in[13];
    const float* outW = (const float*)d_in[14];
    float* out = (float*)d_out;
    char* ws = (char*)d_ws;

    float* denom = (float*)ws;                // 256 f32
    float* ltgt = (float*)(ws + 1024);        // 256 f32
    size_t off = 4096;
    float* emb = (float*)(ws + off);   off += (size_t)2 * TT * Hh * 4;
    float* P = (float*)(ws + off);     off += (size_t)2 * TT * Hh * 4;
    float* h_seq = (float*)(ws + off); off += (size_t)257 * Hh * 4;
    float* Hd = (float*)(ws + off);    off += (size_t)256 * Hh * 4;
    f16* Wreg = (f16*)(ws + off);      off += (size_t)2 * 512 * REGC * 2;
    f16* WldsG = (f16*)(ws + off);     off += (size_t)2 * NLDS * 512 * 8 * 2;
    f16* WL2 = (f16*)(ws + off);       off += (size_t)2 * NL2 * 512 * 8 * 2;
    float* Zb = (float*)(ws + off);    off += (size_t)TT * Hh * 4;

    hipMemsetAsync(ws, 0, 4096, stream);  // denom + ltgt
    k_emb<<<512, 256, 0, stream>>>(src, tgt, enc_emb, dec_emb, emb);
    k_init<<<2, 256, 0, stream>>>(enc_h0, dec_h0, h_seq, Hd);
    k_cvt<<<1024, 64, 0, stream>>>(enc_Whh, dec_Whh, Wreg, WldsG, WL2);
    k_proj<<<dim3(256, 2), 256, 0, stream>>>(emb, enc_Whi, enc_b, dec_Whi, dec_b, P);
    k_chain<<<2, 512, 0, stream>>>(Wreg, WldsG, WL2, P, enc_h0, dec_h0, h_seq, Hd);
    k_attn<<<256, 256, 0, stream>>>(h_seq, Hd, tnhW, tnhb, Zb);
    k_logits<<<VTOT / VTILE, 256, 0, stream>>>(Zb, outW, tgt, denom, ltgt);
    k_final<<<1, 256, 0, stream>>>(denom, ltgt, out);
}

// Round 3
// 693.122 us; speedup vs baseline: 2.3462x; 1.2387x over previous
//
#include <hip/hip_runtime.h>

typedef _Float16 f16;
typedef _Float16 f16x2 __attribute__((ext_vector_type(2)));
typedef _Float16 half8 __attribute__((ext_vector_type(8)));
typedef float f32x4 __attribute__((ext_vector_type(4)));

#define Hh 512
#define TT 256
#define VTOT 32000

__device__ inline float fdot2(unsigned int a, unsigned int b, float c) {
    return __builtin_amdgcn_fdot2(__builtin_bit_cast(f16x2, a),
                                  __builtin_bit_cast(f16x2, b), c, false);
}

__device__ inline float block_sum(float v, float* red) {
#pragma unroll
    for (int o = 1; o < 64; o <<= 1) v += __shfl_xor(v, o);
    if ((threadIdx.x & 63) == 0) red[threadIdx.x >> 6] = v;
    __syncthreads();
    v = red[0] + red[1] + red[2] + red[3];
    __syncthreads();
    return v;
}

__device__ inline float block_max(float v, float* red) {
#pragma unroll
    for (int o = 1; o < 64; o <<= 1) v = fmaxf(v, __shfl_xor(v, o));
    if ((threadIdx.x & 63) == 0) red[threadIdx.x >> 6] = v;
    __syncthreads();
    v = fmaxf(fmaxf(red[0], red[1]), fmaxf(red[2], red[3]));
    __syncthreads();
    return v;
}

// ---- embeddings: gather + L2-normalize. grid 512, 256 thr
__global__ void __launch_bounds__(256) k_emb(const int* __restrict__ src,
                                             const int* __restrict__ tgt,
                                             const float* __restrict__ encW,
                                             const float* __restrict__ decW,
                                             float* __restrict__ emb) {
    const int c = blockIdx.x >> 8, t = blockIdx.x & 255, tid = threadIdx.x;
    const int idx = c ? tgt[t] : src[t];
    const float* row = (c ? decW : encW) + (size_t)idx * Hh;
    float2 v = ((const float2*)row)[tid];
    __shared__ float red[4];
    float tot = block_sum(v.x * v.x + v.y * v.y, red);
    float inv = 1.f / fmaxf(sqrtf(tot), 1e-12f);
    float* orow = emb + ((size_t)c * TT + t) * Hh;
    float2 o;
    o.x = v.x * inv;
    o.y = v.y * inv;
    ((float2*)orow)[tid] = o;
}

// ---- init h_seq[0], Hd[0]. grid 2, 256 thr
__global__ void k_init(const float* __restrict__ eh0, const float* __restrict__ dh0,
                       float* __restrict__ h_seq, float* __restrict__ Hd) {
    const int c = blockIdx.x, tid = threadIdx.x;
    const float* h0 = c ? dh0 : eh0;
    float2 v = ((const float2*)h0)[tid];
    if (c == 0)
        ((float2*)h_seq)[tid] = v;
    else
        ((float2*)Hd)[tid] = v;
}

// ---- W_hh f32 -> f16 in the three k_chain layouts. grid 256 x 256 thr.
// Chunk ci of thread tid5 (rp=tid5>>2, q=tid5&3): row = ci<16 ? rp : rp+256,
// cols q*128 + (ci&15)*8. ci 0..19 -> Wreg, 20..27 -> Wlds, 28..31 -> WL2.
__global__ void k_cvt(const float* __restrict__ enc, const float* __restrict__ dec,
                      f16* __restrict__ Wreg, f16* __restrict__ Wlds,
                      f16* __restrict__ WL2) {
    const int gid = blockIdx.x * 256 + threadIdx.x;  // [0, 65536)
    const int c = gid >> 15;
    const int ci = (gid >> 10) & 31;
    const int tid5 = gid & 1023;
    const int rp = tid5 >> 2, q = tid5 & 3;
    const int row = (ci < 16) ? rp : rp + 256;
    const int col = q * 128 + (ci & 15) * 8;
    const float* s = (c ? dec : enc) + (size_t)row * Hh + col;
    float4 v0 = ((const float4*)s)[0];
    float4 v1 = ((const float4*)s)[1];
    f16x2 p0 = {(f16)v0.x, (f16)v0.y};
    f16x2 p1 = {(f16)v0.z, (f16)v0.w};
    f16x2 p2 = {(f16)v1.x, (f16)v1.y};
    f16x2 p3 = {(f16)v1.z, (f16)v1.w};
    uint4 u;
    u.x = __builtin_bit_cast(unsigned, p0);
    u.y = __builtin_bit_cast(unsigned, p1);
    u.z = __builtin_bit_cast(unsigned, p2);
    u.w = __builtin_bit_cast(unsigned, p3);
    uint4* dst;
    if (ci < 20)
        dst = (uint4*)Wreg + ((size_t)(c * 20 + ci) * 1024 + tid5);
    else if (ci < 28)
        dst = (uint4*)Wlds + ((size_t)(c * 8 + (ci - 20)) * 1024 + tid5);
    else
        dst = (uint4*)WL2 + ((size_t)(c * 4 + (ci - 28)) * 1024 + tid5);
    *dst = u;
}

// ---- P = emb @ W_hi^T + b. grid (64,2), 256 thr, 4 t per block.
__global__ void __launch_bounds__(256) k_proj(const float* __restrict__ emb,
                                              const float* __restrict__ eWhi,
                                              const float* __restrict__ eb,
                                              const float* __restrict__ dWhi,
                                              const float* __restrict__ db,
                                              float* __restrict__ P) {
    const int c = blockIdx.y, t0 = blockIdx.x * 4, tid = threadIdx.x;
    const float* Wv = c ? dWhi : eWhi;
    const float* b = c ? db : eb;
    __shared__ __align__(16) float esh[4][Hh];
#pragma unroll
    for (int r = 0; r < 4; ++r) {
        ((float2*)esh[r])[tid] =
            ((const float2*)(emb + ((size_t)c * TT + t0 + r) * Hh))[tid];
    }
    __syncthreads();
    const int i0 = tid, i1 = tid + 256;
    const float4* w0p = (const float4*)(Wv + (size_t)i0 * Hh);
    const float4* w1p = (const float4*)(Wv + (size_t)i1 * Hh);
    float acc0[4] = {0.f, 0.f, 0.f, 0.f}, acc1[4] = {0.f, 0.f, 0.f, 0.f};
    for (int j = 0; j < Hh / 4; ++j) {
        float4 w0 = w0p[j], w1 = w1p[j];
#pragma unroll
        for (int r = 0; r < 4; ++r) {
            float4 e = ((const float4*)esh[r])[j];
            acc0[r] += w0.x * e.x + w0.y * e.y + w0.z * e.z + w0.w * e.w;
            acc1[r] += w1.x * e.x + w1.y * e.y + w1.z * e.z + w1.w * e.w;
        }
    }
    float b0 = b[i0], b1 = b[i1];
#pragma unroll
    for (int r = 0; r < 4; ++r) {
        P[((size_t)c * TT + t0 + r) * Hh + i0] = acc0[r] + b0;
        P[((size_t)c * TT + t0 + r) * Hh + i1] = acc1[r] + b1;
    }
}

// ---- sequential RNN chains. grid 2, 1024 thr (16 waves, 4/SIMD).
// Thread: rp=tid>>2 rows (rp, rp+256), q=tid&3 cols [q*128, q*128+128).
// W per thread 32 uint4: 20 reg + 8 LDS + 4 L2-streamed. h via skewed LDS.
__global__ void __launch_bounds__(1024, 4) k_chain(
    const f16* __restrict__ Wreg, const f16* __restrict__ WldsG,
    const f16* __restrict__ WL2, const float* __restrict__ P,
    const float* __restrict__ eh0, const float* __restrict__ dh0,
    float* __restrict__ h_seq, float* __restrict__ Hd) {
    const int c = blockIdx.x, tid = threadIdx.x;
    const int rp = tid >> 2, q = tid & 3;
    __shared__ __align__(16) f16 hbuf[2][544];  // skew: idx = col + (col>>7)*8
    __shared__ __align__(16) f16 wl[8][1024][8];

#pragma unroll
    for (int j = 0; j < 8; ++j) {
        *((uint4*)&wl[j][tid][0]) =
            ((const uint4*)WldsG)[(size_t)(c * 8 + j) * 1024 + tid];
    }
    uint4 wreg[20];
    {
        const uint4* wsrc = (const uint4*)Wreg + (size_t)c * 20 * 1024 + tid;
#pragma unroll
        for (int k = 0; k < 20; ++k) wreg[k] = wsrc[k * 1024];
    }
    if (tid < Hh) {
        float v = (c ? dh0 : eh0)[tid];
        hbuf[0][tid + (tid >> 7) * 8] = (f16)v;
    }
    __syncthreads();

    const float* Pc = P + (size_t)c * TT * Hh;
    const int rmine = (q == 0) ? rp : rp + 256;
    float pv = (q < 2) ? Pc[rmine] : 0.f;
    const uint4* wl2base = (const uint4*)WL2 + (size_t)c * 4 * 1024 + tid;

    for (int step = 0; step < 256; ++step) {
        const int cur = step & 1;
        uint4 wb[4];
#pragma unroll
        for (int j = 0; j < 4; ++j) wb[j] = wl2base[j * 1024];

        float a0x = 0.f, a0y = 0.f, a0z = 0.f, a0w = 0.f;
        float a1x = 0.f, a1y = 0.f, a1z = 0.f, a1w = 0.f;
        const f16* hrow = &hbuf[cur][q * 136];
#pragma unroll
        for (int m = 0; m < 16; ++m) {
            uint4 hv = *((const uint4*)&hrow[m * 8]);
            uint4 w0 = wreg[m];
            uint4 w1;
            if (m < 4)
                w1 = wreg[16 + m];
            else if (m < 12)
                w1 = *((const uint4*)&wl[m - 4][tid][0]);
            else
                w1 = wb[m - 12];
            a0x = fdot2(w0.x, hv.x, a0x);
            a0y = fdot2(w0.y, hv.y, a0y);
            a0z = fdot2(w0.z, hv.z, a0z);
            a0w = fdot2(w0.w, hv.w, a0w);
            a1x = fdot2(w1.x, hv.x, a1x);
            a1y = fdot2(w1.y, hv.y, a1y);
            a1z = fdot2(w1.z, hv.z, a1z);
            a1w = fdot2(w1.w, hv.w, a1w);
        }
        float pr0 = (a0x + a0y) + (a0z + a0w);
        float pr1 = (a1x + a1y) + (a1z + a1w);
        pr0 += __shfl_xor(pr0, 1);
        pr0 += __shfl_xor(pr0, 2);
        pr1 += __shfl_xor(pr1, 1);
        pr1 += __shfl_xor(pr1, 2);
        if (q < 2) {
            float pre = ((q == 0) ? pr0 : pr1) + pv;
            float hnew = tanhf(pre);
            if (step < 255) pv = Pc[(size_t)(step + 1) * Hh + rmine];
            hbuf[cur ^ 1][rmine + (rmine >> 7) * 8] = (f16)hnew;
            if (c == 0)
                h_seq[(size_t)(step + 1) * Hh + rmine] = hnew;
            else if (step < 255)
                Hd[(size_t)(step + 1) * Hh + rmine] = hnew;
        }
        __syncthreads();
    }
}

// ---- attention scores + context for all t. grid 256, 256 thr. Writes CH=[c|h].
__global__ void __launch_bounds__(256) k_scores(const float* __restrict__ h_seq,
                                                const float* __restrict__ Hd,
                                                float* __restrict__ CH) {
    const int t = blockIdx.x, tid = threadIdx.x;
    __shared__ float h[Hh];
    __shared__ float w[257];
    __shared__ float red[4];
    ((float2*)h)[tid] = ((const float2*)(Hd + (size_t)t * Hh))[tid];
    __syncthreads();
    float sc0, sc1 = -3.0e38f;
    {
        const float4* row = (const float4*)(h_seq + (size_t)tid * Hh);
        float a = 0.f;
        for (int j = 0; j < Hh / 4; ++j) {
            float4 v = row[j];
            a += v.x * h[4 * j] + v.y * h[4 * j + 1] + v.z * h[4 * j + 2] +
                 v.w * h[4 * j + 3];
        }
        sc0 = a;
    }
    if (tid == 0) {
        const float4* row = (const float4*)(h_seq + (size_t)256 * Hh);
        float a = 0.f;
        for (int j = 0; j < Hh / 4; ++j) {
            float4 v = row[j];
            a += v.x * h[4 * j] + v.y * h[4 * j + 1] + v.z * h[4 * j + 2] +
                 v.w * h[4 * j + 3];
        }
        sc1 = a;
    }
    float m = block_max(fmaxf(sc0, sc1), red);
    float e0 = expf(sc0 - m);
    float e1 = (tid == 0) ? expf(sc1 - m) : 0.f;
    float tot = block_sum(e0 + e1, red);
    float inv = 1.f / tot;
    w[tid] = e0 * inv;
    if (tid == 0) w[256] = e1 * inv;
    __syncthreads();
    float* chrow = CH + (size_t)t * (2 * Hh);
#pragma unroll
    for (int r = 0; r < 2; ++r) {
        int j = tid + r * 256;
        float a = 0.f;
        for (int s = 0; s < 257; ++s) a += w[s] * h_seq[(size_t)s * Hh + j];
        chrow[j] = a;
    }
    ((float2*)(chrow + Hh))[tid] = ((const float2*)h)[tid];
}

// ---- Z = tanh(CH @ tnhW^T + b) as f16. grid 64, 256 thr, 4 t per block.
__global__ void __launch_bounds__(256) k_zgemm(const float* __restrict__ CH,
                                               const float* __restrict__ tnhW,
                                               const float* __restrict__ tnhb,
                                               f16* __restrict__ Zh) {
    const int t0 = blockIdx.x * 4, tid = threadIdx.x;
    __shared__ __align__(16) float chs[4][2 * Hh];
#pragma unroll
    for (int r = 0; r < 4; ++r) {
        ((float4*)chs[r])[tid] = ((const float4*)(CH + (size_t)(t0 + r) * 2 * Hh))[tid];
    }
    __syncthreads();
    const int i0 = tid, i1 = tid + 256;
    const float4* w0p = (const float4*)(tnhW + (size_t)i0 * 2 * Hh);
    const float4* w1p = (const float4*)(tnhW + (size_t)i1 * 2 * Hh);
    float acc0[4] = {0.f, 0.f, 0.f, 0.f}, acc1[4] = {0.f, 0.f, 0.f, 0.f};
    for (int j = 0; j < 2 * Hh / 4; ++j) {
        float4 w0 = w0p[j], w1 = w1p[j];
#pragma unroll
        for (int r = 0; r < 4; ++r) {
            float4 e = ((const float4*)chs[r])[j];
            acc0[r] += w0.x * e.x + w0.y * e.y + w0.z * e.z + w0.w * e.w;
            acc1[r] += w1.x * e.x + w1.y * e.y + w1.z * e.z + w1.w * e.w;
        }
    }
    float b0 = tnhb[i0], b1 = tnhb[i1];
#pragma unroll
    for (int r = 0; r < 4; ++r) {
        Zh[(size_t)(t0 + r) * Hh + i0] = (f16)tanhf(acc0[r] + b0);
        Zh[(size_t)(t0 + r) * Hh + i1] = (f16)tanhf(acc1[r] + b1);
    }
}

// ---- logits via f16 MFMA + fused exp-sum. grid 500 (64 vocab rows), 256 thr.
__global__ void __launch_bounds__(256) k_logits(const f16* __restrict__ Zh,
                                                const float* __restrict__ outW,
                                                const int* __restrict__ tgt,
                                                float* __restrict__ denom,
                                                float* __restrict__ ltgt) {
    const int v0 = blockIdx.x * 64, tid = threadIdx.x;
    const int w = tid >> 6, l = tid & 63;
    const int l15 = l & 15, l4 = l >> 4;
    __shared__ __align__(16) f16 Wt[64][136];
    __shared__ __align__(16) f16 Zt[256][136];
    __shared__ float tsum[4][256];
    __shared__ int tgs[256];
    if (tid < 256) tgs[tid] = tgt[tid];

    f32x4 acc[16];
#pragma unroll
    for (int tt = 0; tt < 16; ++tt) acc[tt] = (f32x4){0.f, 0.f, 0.f, 0.f};

    for (int kc = 0; kc < 4; ++kc) {
        const int k0 = kc * 128;
        // stage W tile 64x128 (f32 -> f16)
#pragma unroll
        for (int p = 0; p < 8; ++p) {
            int g = p * 256 + tid;  // [0,2048)
            int row = g >> 5, f4 = g & 31;
            float4 v = *((const float4*)(outW + (size_t)(v0 + row) * Hh + k0 + f4 * 4));
            f16x2 lo = {(f16)v.x, (f16)v.y};
            f16x2 hi = {(f16)v.z, (f16)v.w};
            uint2 u;
            u.x = __builtin_bit_cast(unsigned, lo);
            u.y = __builtin_bit_cast(unsigned, hi);
            *((uint2*)&Wt[row][f4 * 4]) = u;
        }
        // stage Z tile 256x128 (already f16)
#pragma unroll
        for (int p = 0; p < 16; ++p) {
            int g = p * 256 + tid;  // [0,4096)
            int row = g >> 4, u = g & 15;
            *((uint4*)&Zt[row][u * 8]) =
                *((const uint4*)(Zh + (size_t)row * Hh + k0 + u * 8));
        }
        __syncthreads();
        half8 a[4];
#pragma unroll
        for (int ks = 0; ks < 4; ++ks)
            a[ks] = *((const half8*)&Wt[w * 16 + l15][ks * 32 + l4 * 8]);
#pragma unroll
        for (int tt = 0; tt < 16; ++tt) {
#pragma unroll
            for (int ks = 0; ks < 4; ++ks) {
                half8 b = *((const half8*)&Zt[tt * 16 + l15][ks * 32 + l4 * 8]);
                acc[tt] = __builtin_amdgcn_mfma_f32_16x16x32_f16(a[ks], b, acc[tt],
                                                                 0, 0, 0);
            }
        }
        __syncthreads();
    }
    // exp-sum + target extraction. lane holds logits for v = v0+w*16+l4*4+r,
    // t = tt*16+l15.
    const int vbase = v0 + w * 16 + l4 * 4;
#pragma unroll
    for (int tt = 0; tt < 16; ++tt) {
        float e = __expf(acc[tt][0]) + __expf(acc[tt][1]) + __expf(acc[tt][2]) +
                  __expf(acc[tt][3]);
        e += __shfl_xor(e, 16);
        e += __shfl_xor(e, 32);
        if (l4 == 0) tsum[w][tt * 16 + l15] = e;
        int tglob = tt * 16 + l15;
        int rel = tgs[tglob] - vbase;
        if (rel >= 0 && rel < 4) {
            float val = (rel == 0) ? acc[tt][0]
                        : (rel == 1) ? acc[tt][1]
                        : (rel == 2) ? acc[tt][2]
                                     : acc[tt][3];
            ltgt[tglob] = val;
        }
    }
    __syncthreads();
    if (tid < 256) {
        float s = tsum[0][tid] + tsum[1][tid] + tsum[2][tid] + tsum[3][tid];
        atomicAdd(&denom[tid], s);
    }
}

// ---- final: mean over t of log(denom)-ltgt. grid 1, 256 thr
__global__ void k_final(const float* __restrict__ denom, const float* __restrict__ ltgt,
                        float* __restrict__ out) {
    const int t = threadIdx.x;
    float nll = logf(denom[t]) - ltgt[t];
    __shared__ float red[4];
    float v = nll;
#pragma unroll
    for (int o = 1; o < 64; o <<= 1) v += __shfl_xor(v, o);
    if ((t & 63) == 0) red[t >> 6] = v;
    __syncthreads();
    if (t == 0) out[0] = (red[0] + red[1] + red[2] + red[3]) * (1.f / 256.f);
}

extern "C" void kernel_launch(void* const* d_in, const int* in_sizes, int n_in,
                              void* d_out, int out_size, void* d_ws, size_t ws_size,
                              hipStream_t stream) {
    (void)in_sizes; (void)n_in; (void)out_size; (void)ws_size;
    const int* src = (const int*)d_in[0];
    const int* tgt = (const int*)d_in[1];
    const float* enc_emb = (const float*)d_in[2];
    const float* enc_h0 = (const float*)d_in[3];
    const float* enc_Whi = (const float*)d_in[4];
    const float* enc_Whh = (const float*)d_in[5];
    const float* enc_b = (const float*)d_in[6];
    const float* dec_emb = (const float*)d_in[7];
    const float* dec_h0 = (const float*)d_in[8];
    const float* dec_Whi = (const float*)d_in[9];
    const float* dec_Whh = (const float*)d_in[10];
    const float* dec_b = (const float*)d_in[11];
    const float* tnhW = (const float*)d_in[12];
    const float* tnhb = (const float*)d_in[13];
    const float* outW = (const float*)d_in[14];
    float* out = (float*)d_out;
    char* ws = (char*)d_ws;

    float* denom = (float*)ws;           // 256 f32
    float* ltgt = (float*)(ws + 1024);   // 256 f32
    size_t off = 4096;
    float* emb = (float*)(ws + off);   off += (size_t)2 * TT * Hh * 4;      // 1MB
    float* P = (float*)(ws + off);     off += (size_t)2 * TT * Hh * 4;      // 1MB
    float* h_seq = (float*)(ws + off); off += (size_t)264 * Hh * 4;         // 528KB
    float* Hd = (float*)(ws + off);    off += (size_t)256 * Hh * 4;         // 512KB
    float* CH = (float*)(ws + off);    off += (size_t)TT * 2 * Hh * 4;      // 1MB
    f16* Zh = (f16*)(ws + off);        off += (size_t)TT * Hh * 2;          // 256KB
    f16* Wreg = (f16*)(ws + off);      off += (size_t)2 * 20 * 1024 * 16;   // 640KB
    f16* Wlds = (f16*)(ws + off);      off += (size_t)2 * 8 * 1024 * 16;    // 256KB
    f16* WL2 = (f16*)(ws + off);       off += (size_t)2 * 4 * 1024 * 16;    // 128KB

    hipMemsetAsync(ws, 0, 4096, stream);  // denom + ltgt
    k_cvt<<<256, 256, 0, stream>>>(enc_Whh, dec_Whh, Wreg, Wlds, WL2);
    k_emb<<<512, 256, 0, stream>>>(src, tgt, enc_emb, dec_emb, emb);
    k_init<<<2, 256, 0, stream>>>(enc_h0, dec_h0, h_seq, Hd);
    k_proj<<<dim3(64, 2), 256, 0, stream>>>(emb, enc_Whi, enc_b, dec_Whi, dec_b, P);
    k_chain<<<2, 1024, 0, stream>>>(Wreg, Wlds, WL2, P, enc_h0, dec_h0, h_seq, Hd);
    k_scores<<<256, 256, 0, stream>>>(h_seq, Hd, CH);
    k_zgemm<<<64, 256, 0, stream>>>(CH, tnhW, tnhb, Zh);
    k_logits<<<500, 256, 0, stream>>>(Zh, outW, tgt, denom, ltgt);
    k_final<<<1, 256, 0, stream>>>(denom, ltgt, out);
}

// Round 5
// 587.061 us; speedup vs baseline: 2.7701x; 1.1807x over previous
//
#include <hip/hip_runtime.h>

typedef _Float16 f16;
typedef _Float16 f16x2 __attribute__((ext_vector_type(2)));
typedef _Float16 half8 __attribute__((ext_vector_type(8)));
typedef float f32x4 __attribute__((ext_vector_type(4)));

#define Hh 512
#define TT 256
#define VTOT 32000

__device__ inline float fdot2(unsigned int a, unsigned int b, float c) {
    return __builtin_amdgcn_fdot2(__builtin_bit_cast(f16x2, a),
                                  __builtin_bit_cast(f16x2, b), c, false);
}

__device__ inline float tanh_fast(float x) {
    float ax = fabsf(x);
    float t = __expf(-2.f * ax);
    float th = (1.f - t) * __builtin_amdgcn_rcpf(1.f + t);
    return copysignf(th, x);
}

__device__ inline float block_sum(float v, float* red) {
#pragma unroll
    for (int o = 1; o < 64; o <<= 1) v += __shfl_xor(v, o);
    if ((threadIdx.x & 63) == 0) red[threadIdx.x >> 6] = v;
    __syncthreads();
    v = red[0] + red[1] + red[2] + red[3];
    __syncthreads();
    return v;
}

__device__ inline float block_max(float v, float* red) {
#pragma unroll
    for (int o = 1; o < 64; o <<= 1) v = fmaxf(v, __shfl_xor(v, o));
    if ((threadIdx.x & 63) == 0) red[threadIdx.x >> 6] = v;
    __syncthreads();
    v = fmaxf(fmaxf(red[0], red[1]), fmaxf(red[2], red[3]));
    __syncthreads();
    return v;
}

// ---- embeddings: gather + L2-normalize. grid 512, 256 thr
__global__ void __launch_bounds__(256) k_emb(const int* __restrict__ src,
                                             const int* __restrict__ tgt,
                                             const float* __restrict__ encW,
                                             const float* __restrict__ decW,
                                             float* __restrict__ emb) {
    const int c = blockIdx.x >> 8, t = blockIdx.x & 255, tid = threadIdx.x;
    const int idx = c ? tgt[t] : src[t];
    const float* row = (c ? decW : encW) + (size_t)idx * Hh;
    float2 v = ((const float2*)row)[tid];
    __shared__ float red[4];
    float tot = block_sum(v.x * v.x + v.y * v.y, red);
    float inv = 1.f / fmaxf(sqrtf(tot), 1e-12f);
    float* orow = emb + ((size_t)c * TT + t) * Hh;
    float2 o;
    o.x = v.x * inv;
    o.y = v.y * inv;
    ((float2*)orow)[tid] = o;
}

// ---- init h_seq[0], Hd[0]. grid 2, 256 thr
__global__ void k_init(const float* __restrict__ eh0, const float* __restrict__ dh0,
                       float* __restrict__ h_seq, float* __restrict__ Hd) {
    const int c = blockIdx.x, tid = threadIdx.x;
    const float* h0 = c ? dh0 : eh0;
    float2 v = ((const float2*)h0)[tid];
    if (c == 0)
        ((float2*)h_seq)[tid] = v;
    else
        ((float2*)Hd)[tid] = v;
}

// ---- W_hh f32 -> f16, three layouts for k_chain. grid 256 x 256 thr.
// Thread (q=t5>>6, rg=t5&63) owns rows {64j+rg}, cols [64q,64q+64).
// j=0..4 -> Wreg; j=5 -> Wlds; j=6,7 -> WL2. Entry m covers cols 64q+8m..+7.
__global__ void k_cvt(const float* __restrict__ enc, const float* __restrict__ dec,
                      uint4* __restrict__ Wreg, uint4* __restrict__ Wlds,
                      uint4* __restrict__ WL2) {
    const int gid = blockIdx.x * 256 + threadIdx.x;  // [0, 65536)
    const int c = gid >> 15;
    const int r = gid & 32767;
    const int j = r >> 12;
    const int m = (r >> 9) & 7;
    const int t5 = r & 511;
    const int q = t5 >> 6, rg = t5 & 63;
    const int row = 64 * j + rg;
    const int col = 64 * q + 8 * m;
    const float* s = (c ? dec : enc) + (size_t)row * Hh + col;
    float4 v0 = ((const float4*)s)[0];
    float4 v1 = ((const float4*)s)[1];
    f16x2 p0 = {(f16)v0.x, (f16)v0.y};
    f16x2 p1 = {(f16)v0.z, (f16)v0.w};
    f16x2 p2 = {(f16)v1.x, (f16)v1.y};
    f16x2 p3 = {(f16)v1.z, (f16)v1.w};
    uint4 u;
    u.x = __builtin_bit_cast(unsigned, p0);
    u.y = __builtin_bit_cast(unsigned, p1);
    u.z = __builtin_bit_cast(unsigned, p2);
    u.w = __builtin_bit_cast(unsigned, p3);
    if (j < 5)
        Wreg[((size_t)(c * 5 + j) * 8 + m) * 512 + t5] = u;
    else if (j == 5)
        Wlds[((size_t)c * 8 + m) * 512 + t5] = u;
    else
        WL2[((size_t)(c * 2 + (j - 6)) * 8 + m) * 512 + t5] = u;
}

// ---- P = emb @ W_hi^T + b. grid (64,2), 256 thr, 4 t per block.
__global__ void __launch_bounds__(256) k_proj(const float* __restrict__ emb,
                                              const float* __restrict__ eWhi,
                                              const float* __restrict__ eb,
                                              const float* __restrict__ dWhi,
                                              const float* __restrict__ db,
                                              float* __restrict__ P) {
    const int c = blockIdx.y, t0 = blockIdx.x * 4, tid = threadIdx.x;
    const float* Wv = c ? dWhi : eWhi;
    const float* b = c ? db : eb;
    __shared__ __align__(16) float esh[4][Hh];
#pragma unroll
    for (int r = 0; r < 4; ++r) {
        ((float2*)esh[r])[tid] =
            ((const float2*)(emb + ((size_t)c * TT + t0 + r) * Hh))[tid];
    }
    __syncthreads();
    const int i0 = tid, i1 = tid + 256;
    const float4* w0p = (const float4*)(Wv + (size_t)i0 * Hh);
    const float4* w1p = (const float4*)(Wv + (size_t)i1 * Hh);
    float acc0[4] = {0.f, 0.f, 0.f, 0.f}, acc1[4] = {0.f, 0.f, 0.f, 0.f};
    for (int j = 0; j < Hh / 4; ++j) {
        float4 w0 = w0p[j], w1 = w1p[j];
#pragma unroll
        for (int r = 0; r < 4; ++r) {
            float4 e = ((const float4*)esh[r])[j];
            acc0[r] += w0.x * e.x + w0.y * e.y + w0.z * e.z + w0.w * e.w;
            acc1[r] += w1.x * e.x + w1.y * e.y + w1.z * e.z + w1.w * e.w;
        }
    }
    float b0 = b[i0], b1 = b[i1];
#pragma unroll
    for (int r = 0; r < 4; ++r) {
        P[((size_t)c * TT + t0 + r) * Hh + i0] = acc0[r] + b0;
        P[((size_t)c * TT + t0 + r) * Hh + i1] = acc1[r] + b1;
    }
}

#define DOT(Av, Wv, Hv)             \
    Av = fdot2((Wv).x, (Hv).x, Av); \
    Av = fdot2((Wv).y, (Hv).y, Av); \
    Av = fdot2((Wv).z, (Hv).z, Av); \
    Av = fdot2((Wv).w, (Hv).w, Av);

// ---- sequential RNN chains. grid 2, 512 thr (8 waves, 2/SIMD).
// Thread (q=tid>>6, rg=tid&63): rows {64j+rg} j=0..7, cols [64q, 64q+64).
// W: j0-4 regs (160 VGPR), j5 LDS, j6/j7 L2-streamed (step-invariant).
// h broadcast from LDS (wave-uniform q); cross-wave reduce via part[8][520].
__global__ void __launch_bounds__(512, 2) k_chain(
    const uint4* __restrict__ Wreg, const uint4* __restrict__ WldsG,
    const uint4* __restrict__ WL2, const float* __restrict__ P,
    const float* __restrict__ eh0, const float* __restrict__ dh0,
    float* __restrict__ h_seq, float* __restrict__ Hd) {
    const int c = blockIdx.x, tid = threadIdx.x;
    const int q = tid >> 6, rg = tid & 63;
    __shared__ uint4 wl[8][512];    // 64KB: j=5 slab
    __shared__ float part[8][520];  // 16.6KB partial sums
    __shared__ __align__(16) f16 hbuf[2][Hh];

#pragma unroll
    for (int m = 0; m < 8; ++m)
        wl[m][tid] = WldsG[((size_t)c * 8 + m) * 512 + tid];
    uint4 wr[5][8];
#pragma unroll
    for (int j = 0; j < 5; ++j)
#pragma unroll
        for (int m = 0; m < 8; ++m)
            wr[j][m] = Wreg[((size_t)(c * 5 + j) * 8 + m) * 512 + tid];
    hbuf[0][tid] = (f16)((c ? dh0 : eh0)[tid]);
    __syncthreads();

    const float* Pc = P + (size_t)c * TT * Hh;
    float pv = Pc[tid];
    const uint4* Ab = WL2 + ((size_t)c * 2 + 0) * 8 * 512 + tid;
    const uint4* Bb = WL2 + ((size_t)c * 2 + 1) * 8 * 512 + tid;

    for (int step = 0; step < 256; ++step) {
        const f16* hc = hbuf[step & 1];
        float acc0 = 0.f, acc1 = 0.f, acc2 = 0.f, acc3 = 0.f;
        float acc4 = 0.f, acc5 = 0.f, acc6 = 0.f, acc7 = 0.f;
        // L2 prefetch batch 1 (m=0..3 of both streamed slabs)
        uint4 a0 = Ab[0 * 512], a1 = Ab[1 * 512], a2 = Ab[2 * 512], a3 = Ab[3 * 512];
        uint4 b0 = Bb[0 * 512], b1 = Bb[1 * 512], b2 = Bb[2 * 512], b3 = Bb[3 * 512];
        // ---- mb0: m=0,1
        {
            uint4 hv0 = *((const uint4*)&hc[q * 64 + 0]);
            uint4 hv1 = *((const uint4*)&hc[q * 64 + 8]);
            DOT(acc0, wr[0][0], hv0) DOT(acc0, wr[0][1], hv1)
            DOT(acc1, wr[1][0], hv0) DOT(acc1, wr[1][1], hv1)
            DOT(acc2, wr[2][0], hv0) DOT(acc2, wr[2][1], hv1)
            DOT(acc3, wr[3][0], hv0) DOT(acc3, wr[3][1], hv1)
            DOT(acc4, wr[4][0], hv0) DOT(acc4, wr[4][1], hv1)
            uint4 w50 = wl[0][tid], w51 = wl[1][tid];
            DOT(acc5, w50, hv0) DOT(acc5, w51, hv1)
            DOT(acc6, a0, hv0) DOT(acc6, a1, hv1)
            DOT(acc7, b0, hv0) DOT(acc7, b1, hv1)
        }
        // L2 prefetch batch 2 (m=4..7)
        uint4 a4 = Ab[4 * 512], a5 = Ab[5 * 512], a6 = Ab[6 * 512], a7 = Ab[7 * 512];
        uint4 b4 = Bb[4 * 512], b5 = Bb[5 * 512], b6 = Bb[6 * 512], b7 = Bb[7 * 512];
        // ---- mb1: m=2,3
        {
            uint4 hv0 = *((const uint4*)&hc[q * 64 + 16]);
            uint4 hv1 = *((const uint4*)&hc[q * 64 + 24]);
            DOT(acc0, wr[0][2], hv0) DOT(acc0, wr[0][3], hv1)
            DOT(acc1, wr[1][2], hv0) DOT(acc1, wr[1][3], hv1)
            DOT(acc2, wr[2][2], hv0) DOT(acc2, wr[2][3], hv1)
            DOT(acc3, wr[3][2], hv0) DOT(acc3, wr[3][3], hv1)
            DOT(acc4, wr[4][2], hv0) DOT(acc4, wr[4][3], hv1)
            uint4 w50 = wl[2][tid], w51 = wl[3][tid];
            DOT(acc5, w50, hv0) DOT(acc5, w51, hv1)
            DOT(acc6, a2, hv0) DOT(acc6, a3, hv1)
            DOT(acc7, b2, hv0) DOT(acc7, b3, hv1)
        }
        // ---- mb2: m=4,5
        {
            uint4 hv0 = *((const uint4*)&hc[q * 64 + 32]);
            uint4 hv1 = *((const uint4*)&hc[q * 64 + 40]);
            DOT(acc0, wr[0][4], hv0) DOT(acc0, wr[0][5], hv1)
            DOT(acc1, wr[1][4], hv0) DOT(acc1, wr[1][5], hv1)
            DOT(acc2, wr[2][4], hv0) DOT(acc2, wr[2][5], hv1)
            DOT(acc3, wr[3][4], hv0) DOT(acc3, wr[3][5], hv1)
            DOT(acc4, wr[4][4], hv0) DOT(acc4, wr[4][5], hv1)
            uint4 w50 = wl[4][tid], w51 = wl[5][tid];
            DOT(acc5, w50, hv0) DOT(acc5, w51, hv1)
            DOT(acc6, a4, hv0) DOT(acc6, a5, hv1)
            DOT(acc7, b4, hv0) DOT(acc7, b5, hv1)
        }
        // ---- mb3: m=6,7
        {
            uint4 hv0 = *((const uint4*)&hc[q * 64 + 48]);
            uint4 hv1 = *((const uint4*)&hc[q * 64 + 56]);
            DOT(acc0, wr[0][6], hv0) DOT(acc0, wr[0][7], hv1)
            DOT(acc1, wr[1][6], hv0) DOT(acc1, wr[1][7], hv1)
            DOT(acc2, wr[2][6], hv0) DOT(acc2, wr[2][7], hv1)
            DOT(acc3, wr[3][6], hv0) DOT(acc3, wr[3][7], hv1)
            DOT(acc4, wr[4][6], hv0) DOT(acc4, wr[4][7], hv1)
            uint4 w50 = wl[6][tid], w51 = wl[7][tid];
            DOT(acc5, w50, hv0) DOT(acc5, w51, hv1)
            DOT(acc6, a6, hv0) DOT(acc6, a7, hv1)
            DOT(acc7, b6, hv0) DOT(acc7, b7, hv1)
        }
        // partials: row 64j+rg of col-slice q
        part[q][0 * 64 + rg] = acc0;
        part[q][1 * 64 + rg] = acc1;
        part[q][2 * 64 + rg] = acc2;
        part[q][3 * 64 + rg] = acc3;
        part[q][4 * 64 + rg] = acc4;
        part[q][5 * 64 + rg] = acc5;
        part[q][6 * 64 + rg] = acc6;
        part[q][7 * 64 + rg] = acc7;
        __syncthreads();
        // finalize: this thread owns output row == tid
        float s = ((part[0][tid] + part[1][tid]) + (part[2][tid] + part[3][tid])) +
                  ((part[4][tid] + part[5][tid]) + (part[6][tid] + part[7][tid]));
        float pre = s + pv;
        float hnew = tanh_fast(pre);
        if (step < 255) pv = Pc[(size_t)(step + 1) * Hh + tid];
        hbuf[(step + 1) & 1][tid] = (f16)hnew;
        if (c == 0)
            h_seq[(size_t)(step + 1) * Hh + tid] = hnew;
        else if (step < 255)
            Hd[(size_t)(step + 1) * Hh + tid] = hnew;
        __syncthreads();
    }
}

// ---- attention scores + context for all t. grid 256, 256 thr. Writes CH=[c|h].
__global__ void __launch_bounds__(256) k_scores(const float* __restrict__ h_seq,
                                                const float* __restrict__ Hd,
                                                float* __restrict__ CH) {
    const int t = blockIdx.x, tid = threadIdx.x;
    __shared__ float h[Hh];
    __shared__ float w[257];
    __shared__ float red[4];
    ((float2*)h)[tid] = ((const float2*)(Hd + (size_t)t * Hh))[tid];
    __syncthreads();
    float sc0, sc1 = -3.0e38f;
    {
        const float4* row = (const float4*)(h_seq + (size_t)tid * Hh);
        float a = 0.f;
        for (int j = 0; j < Hh / 4; ++j) {
            float4 v = row[j];
            a += v.x * h[4 * j] + v.y * h[4 * j + 1] + v.z * h[4 * j + 2] +
                 v.w * h[4 * j + 3];
        }
        sc0 = a;
    }
    if (tid == 0) {
        const float4* row = (const float4*)(h_seq + (size_t)256 * Hh);
        float a = 0.f;
        for (int j = 0; j < Hh / 4; ++j) {
            float4 v = row[j];
            a += v.x * h[4 * j] + v.y * h[4 * j + 1] + v.z * h[4 * j + 2] +
                 v.w * h[4 * j + 3];
        }
        sc1 = a;
    }
    float m = block_max(fmaxf(sc0, sc1), red);
    float e0 = expf(sc0 - m);
    float e1 = (tid == 0) ? expf(sc1 - m) : 0.f;
    float tot = block_sum(e0 + e1, red);
    float inv = 1.f / tot;
    w[tid] = e0 * inv;
    if (tid == 0) w[256] = e1 * inv;
    __syncthreads();
    float* chrow = CH + (size_t)t * (2 * Hh);
#pragma unroll
    for (int r = 0; r < 2; ++r) {
        int j = tid + r * 256;
        float a = 0.f;
        for (int s = 0; s < 257; ++s) a += w[s] * h_seq[(size_t)s * Hh + j];
        chrow[j] = a;
    }
    ((float2*)(chrow + Hh))[tid] = ((const float2*)h)[tid];
}

// ---- Z = tanh(CH @ tnhW^T + b) as f16. grid 64, 256 thr, 4 t per block.
__global__ void __launch_bounds__(256) k_zgemm(const float* __restrict__ CH,
                                               const float* __restrict__ tnhW,
                                               const float* __restrict__ tnhb,
                                               f16* __restrict__ Zh) {
    const int t0 = blockIdx.x * 4, tid = threadIdx.x;
    __shared__ __align__(16) float chs[4][2 * Hh];
#pragma unroll
    for (int r = 0; r < 4; ++r) {
        ((float4*)chs[r])[tid] = ((const float4*)(CH + (size_t)(t0 + r) * 2 * Hh))[tid];
    }
    __syncthreads();
    const int i0 = tid, i1 = tid + 256;
    const float4* w0p = (const float4*)(tnhW + (size_t)i0 * 2 * Hh);
    const float4* w1p = (const float4*)(tnhW + (size_t)i1 * 2 * Hh);
    float acc0[4] = {0.f, 0.f, 0.f, 0.f}, acc1[4] = {0.f, 0.f, 0.f, 0.f};
    for (int j = 0; j < 2 * Hh / 4; ++j) {
        float4 w0 = w0p[j], w1 = w1p[j];
#pragma unroll
        for (int r = 0; r < 4; ++r) {
            float4 e = ((const float4*)chs[r])[j];
            acc0[r] += w0.x * e.x + w0.y * e.y + w0.z * e.z + w0.w * e.w;
            acc1[r] += w1.x * e.x + w1.y * e.y + w1.z * e.z + w1.w * e.w;
        }
    }
    float b0 = tnhb[i0], b1 = tnhb[i1];
#pragma unroll
    for (int r = 0; r < 4; ++r) {
        Zh[(size_t)(t0 + r) * Hh + i0] = (f16)tanhf(acc0[r] + b0);
        Zh[(size_t)(t0 + r) * Hh + i1] = (f16)tanhf(acc1[r] + b1);
    }
}

// ---- logits via f16 MFMA + fused exp-sum. grid 500 (64 vocab rows), 256 thr.
__global__ void __launch_bounds__(256) k_logits(const f16* __restrict__ Zh,
                                                const float* __restrict__ outW,
                                                const int* __restrict__ tgt,
                                                float* __restrict__ denom,
                                                float* __restrict__ ltgt) {
    const int v0 = blockIdx.x * 64, tid = threadIdx.x;
    const int w = tid >> 6, l = tid & 63;
    const int l15 = l & 15, l4 = l >> 4;
    __shared__ __align__(16) f16 Wt[64][136];
    __shared__ __align__(16) f16 Zt[256][136];
    __shared__ float tsum[4][256];
    __shared__ int tgs[256];
    if (tid < 256) tgs[tid] = tgt[tid];

    f32x4 acc[16];
#pragma unroll
    for (int tt = 0; tt < 16; ++tt) acc[tt] = (f32x4){0.f, 0.f, 0.f, 0.f};

    for (int kc = 0; kc < 4; ++kc) {
        const int k0 = kc * 128;
#pragma unroll
        for (int p = 0; p < 8; ++p) {
            int g = p * 256 + tid;
            int row = g >> 5, f4 = g & 31;
            float4 v = *((const float4*)(outW + (size_t)(v0 + row) * Hh + k0 + f4 * 4));
            f16x2 lo = {(f16)v.x, (f16)v.y};
            f16x2 hi = {(f16)v.z, (f16)v.w};
            uint2 u;
            u.x = __builtin_bit_cast(unsigned, lo);
            u.y = __builtin_bit_cast(unsigned, hi);
            *((uint2*)&Wt[row][f4 * 4]) = u;
        }
#pragma unroll
        for (int p = 0; p < 16; ++p) {
            int g = p * 256 + tid;
            int row = g >> 4, u = g & 15;
            *((uint4*)&Zt[row][u * 8]) =
                *((const uint4*)(Zh + (size_t)row * Hh + k0 + u * 8));
        }
        __syncthreads();
        half8 a[4];
#pragma unroll
        for (int ks = 0; ks < 4; ++ks)
            a[ks] = *((const half8*)&Wt[w * 16 + l15][ks * 32 + l4 * 8]);
#pragma unroll
        for (int tt = 0; tt < 16; ++tt) {
#pragma unroll
            for (int ks = 0; ks < 4; ++ks) {
                half8 b = *((const half8*)&Zt[tt * 16 + l15][ks * 32 + l4 * 8]);
                acc[tt] = __builtin_amdgcn_mfma_f32_16x16x32_f16(a[ks], b, acc[tt],
                                                                 0, 0, 0);
            }
        }
        __syncthreads();
    }
    const int vbase = v0 + w * 16 + l4 * 4;
#pragma unroll
    for (int tt = 0; tt < 16; ++tt) {
        float e = __expf(acc[tt][0]) + __expf(acc[tt][1]) + __expf(acc[tt][2]) +
                  __expf(acc[tt][3]);
        e += __shfl_xor(e, 16);
        e += __shfl_xor(e, 32);
        if (l4 == 0) tsum[w][tt * 16 + l15] = e;
        int tglob = tt * 16 + l15;
        int rel = tgs[tglob] - vbase;
        if (rel >= 0 && rel < 4) {
            float val = (rel == 0) ? acc[tt][0]
                        : (rel == 1) ? acc[tt][1]
                        : (rel == 2) ? acc[tt][2]
                                     : acc[tt][3];
            ltgt[tglob] = val;
        }
    }
    __syncthreads();
    if (tid < 256) {
        float s = tsum[0][tid] + tsum[1][tid] + tsum[2][tid] + tsum[3][tid];
        atomicAdd(&denom[tid], s);
    }
}

// ---- final: mean over t of log(denom)-ltgt. grid 1, 256 thr
__global__ void k_final(const float* __restrict__ denom, const float* __restrict__ ltgt,
                        float* __restrict__ out) {
    const int t = threadIdx.x;
    float nll = logf(denom[t]) - ltgt[t];
    __shared__ float red[4];
    float v = nll;
#pragma unroll
    for (int o = 1; o < 64; o <<= 1) v += __shfl_xor(v, o);
    if ((t & 63) == 0) red[t >> 6] = v;
    __syncthreads();
    if (t == 0) out[0] = (red[0] + red[1] + red[2] + red[3]) * (1.f / 256.f);
}

extern "C" void kernel_launch(void* const* d_in, const int* in_sizes, int n_in,
                              void* d_out, int out_size, void* d_ws, size_t ws_size,
                              hipStream_t stream) {
    (void)in_sizes; (void)n_in; (void)out_size; (void)ws_size;
    const int* src = (const int*)d_in[0];
    const int* tgt = (const int*)d_in[1];
    const float* enc_emb = (const float*)d_in[2];
    const float* enc_h0 = (const float*)d_in[3];
    const float* enc_Whi = (const float*)d_in[4];
    const float* enc_Whh = (const float*)d_in[5];
    const float* enc_b = (const float*)d_in[6];
    const float* dec_emb = (const float*)d_in[7];
    const float* dec_h0 = (const float*)d_in[8];
    const float* dec_Whi = (const float*)d_in[9];
    const float* dec_Whh = (const float*)d_in[10];
    const float* dec_b = (const float*)d_in[11];
    const float* tnhW = (const float*)d_in[12];
    const float* tnhb = (const float*)d_in[13];
    const float* outW = (const float*)d_in[14];
    float* out = (float*)d_out;
    char* ws = (char*)d_ws;

    float* denom = (float*)ws;           // 256 f32
    float* ltgt = (float*)(ws + 1024);   // 256 f32
    size_t off = 4096;
    float* emb = (float*)(ws + off);   off += (size_t)2 * TT * Hh * 4;      // 1MB
    float* P = (float*)(ws + off);     off += (size_t)2 * TT * Hh * 4;      // 1MB
    float* h_seq = (float*)(ws + off); off += (size_t)264 * Hh * 4;         // 528KB
    float* Hd = (float*)(ws + off);    off += (size_t)256 * Hh * 4;         // 512KB
    float* CH = (float*)(ws + off);    off += (size_t)TT * 2 * Hh * 4;      // 1MB
    f16* Zh = (f16*)(ws + off);        off += (size_t)TT * Hh * 2;          // 256KB
    uint4* Wreg = (uint4*)(ws + off);  off += (size_t)2 * 5 * 8 * 512 * 16; // 640KB
    uint4* Wlds = (uint4*)(ws + off);  off += (size_t)2 * 8 * 512 * 16;     // 128KB
    uint4* WL2 = (uint4*)(ws + off);   off += (size_t)2 * 2 * 8 * 512 * 16; // 256KB

    hipMemsetAsync(ws, 0, 4096, stream);  // denom + ltgt
    k_cvt<<<256, 256, 0, stream>>>(enc_Whh, dec_Whh, Wreg, Wlds, WL2);
    k_emb<<<512, 256, 0, stream>>>(src, tgt, enc_emb, dec_emb, emb);
    k_init<<<2, 256, 0, stream>>>(enc_h0, dec_h0, h_seq, Hd);
    k_proj<<<dim3(64, 2), 256, 0, stream>>>(emb, enc_Whi, enc_b, dec_Whi, dec_b, P);
    k_chain<<<2, 512, 0, stream>>>(Wreg, Wlds, WL2, P, enc_h0, dec_h0, h_seq, Hd);
    k_scores<<<256, 256, 0, stream>>>(h_seq, Hd, CH);
    k_zgemm<<<64, 256, 0, stream>>>(CH, tnhW, tnhb, Zh);
    k_logits<<<500, 256, 0, stream>>>(Zh, outW, tgt, denom, ltgt);
    k_final<<<1, 256, 0, stream>>>(denom, ltgt, out);
}

// Round 6
// 371.580 us; speedup vs baseline: 4.3765x; 1.5799x over previous
//
#include <hip/hip_runtime.h>

typedef _Float16 f16;
typedef _Float16 f16x2 __attribute__((ext_vector_type(2)));
typedef _Float16 half8 __attribute__((ext_vector_type(8)));
typedef float f32x4 __attribute__((ext_vector_type(4)));

#define Hh 512
#define TT 256
#define VTOT 32000
#define HSCALE 1600.0f

__device__ inline int dot4i8(int a, int b, int c) {
#if __has_builtin(__builtin_amdgcn_sdot4)
    return __builtin_amdgcn_sdot4(a, b, c, false);
#else
    int s = c;
#pragma unroll
    for (int i = 0; i < 4; ++i)
        s += (int)(signed char)(a >> (8 * i)) * (int)(signed char)(b >> (8 * i));
    return s;
#endif
}

__device__ inline float tanh_fast(float x) {
    float ax = fabsf(x);
    float t = __expf(-2.f * ax);
    float th = (1.f - t) * __builtin_amdgcn_rcpf(1.f + t);
    return copysignf(th, x);
}

__device__ inline float block_sum(float v, float* red) {
#pragma unroll
    for (int o = 1; o < 64; o <<= 1) v += __shfl_xor(v, o);
    if ((threadIdx.x & 63) == 0) red[threadIdx.x >> 6] = v;
    __syncthreads();
    v = red[0] + red[1] + red[2] + red[3];
    __syncthreads();
    return v;
}

__device__ inline float block_max(float v, float* red) {
#pragma unroll
    for (int o = 1; o < 64; o <<= 1) v = fmaxf(v, __shfl_xor(v, o));
    if ((threadIdx.x & 63) == 0) red[threadIdx.x >> 6] = v;
    __syncthreads();
    v = fmaxf(fmaxf(red[0], red[1]), fmaxf(red[2], red[3]));
    __syncthreads();
    return v;
}

// ---- embeddings: gather + L2-normalize. grid 512, 256 thr
__global__ void __launch_bounds__(256) k_emb(const int* __restrict__ src,
                                             const int* __restrict__ tgt,
                                             const float* __restrict__ encW,
                                             const float* __restrict__ decW,
                                             float* __restrict__ emb) {
    const int c = blockIdx.x >> 8, t = blockIdx.x & 255, tid = threadIdx.x;
    const int idx = c ? tgt[t] : src[t];
    const float* row = (c ? decW : encW) + (size_t)idx * Hh;
    float2 v = ((const float2*)row)[tid];
    __shared__ float red[4];
    float tot = block_sum(v.x * v.x + v.y * v.y, red);
    float inv = 1.f / fmaxf(sqrtf(tot), 1e-12f);
    float* orow = emb + ((size_t)c * TT + t) * Hh;
    float2 o;
    o.x = v.x * inv;
    o.y = v.y * inv;
    ((float2*)orow)[tid] = o;
}

// ---- init h_seq[0], Hd[0]. grid 2, 256 thr
__global__ void k_init(const float* __restrict__ eh0, const float* __restrict__ dh0,
                       float* __restrict__ h_seq, float* __restrict__ Hd) {
    const int c = blockIdx.x, tid = threadIdx.x;
    const float* h0 = c ? dh0 : eh0;
    float2 v = ((const float2*)h0)[tid];
    if (c == 0)
        ((float2*)h_seq)[tid] = v;
    else
        ((float2*)Hd)[tid] = v;
}

// ---- W_hh f32 -> i8 with per-row scale. grid 1024 (c,row), 128 thr.
// Layout (uint4 units): Wq8[ (c*32 + u)*512 + r ], u = col chunk of 16 i8.
// sWf[c*512+r] = rowmax/(127*HSCALE)  (dequant factor for sdot4 acc).
__global__ void __launch_bounds__(128) k_cvt(const float* __restrict__ enc,
                                             const float* __restrict__ dec,
                                             unsigned int* __restrict__ Wq8,
                                             float* __restrict__ sWf) {
    const int c = blockIdx.x >> 9, r = blockIdx.x & 511, tid = threadIdx.x;
    const float* s = (c ? dec : enc) + (size_t)r * Hh + tid * 4;
    float4 v = *((const float4*)s);
    float m4 = fmaxf(fmaxf(fabsf(v.x), fabsf(v.y)), fmaxf(fabsf(v.z), fabsf(v.w)));
#pragma unroll
    for (int o = 1; o < 64; o <<= 1) m4 = fmaxf(m4, __shfl_xor(m4, o));
    __shared__ float red[2];
    if ((tid & 63) == 0) red[tid >> 6] = m4;
    __syncthreads();
    float m = fmaxf(red[0], red[1]);
    m = fmaxf(m, 1e-30f);
    float qs = 127.f / m;
    int q0 = (int)rintf(v.x * qs), q1 = (int)rintf(v.y * qs);
    int q2 = (int)rintf(v.z * qs), q3 = (int)rintf(v.w * qs);
    unsigned int pk = (unsigned int)(q0 & 255) | ((unsigned int)(q1 & 255) << 8) |
                      ((unsigned int)(q2 & 255) << 16) | ((unsigned int)(q3 & 255) << 24);
    const int u = tid >> 2, dw = tid & 3;
    Wq8[(((size_t)(c * 32 + u) * 512 + r) << 2) + dw] = pk;
    if (tid == 0) sWf[c * 512 + r] = m * (1.f / (127.f * HSCALE));
}

// ---- P = emb @ W_hi^T + b. grid (64,2), 256 thr, 4 t per block.
__global__ void __launch_bounds__(256) k_proj(const float* __restrict__ emb,
                                              const float* __restrict__ eWhi,
                                              const float* __restrict__ eb,
                                              const float* __restrict__ dWhi,
                                              const float* __restrict__ db,
                                              float* __restrict__ P) {
    const int c = blockIdx.y, t0 = blockIdx.x * 4, tid = threadIdx.x;
    const float* Wv = c ? dWhi : eWhi;
    const float* b = c ? db : eb;
    __shared__ __align__(16) float esh[4][Hh];
#pragma unroll
    for (int r = 0; r < 4; ++r) {
        ((float2*)esh[r])[tid] =
            ((const float2*)(emb + ((size_t)c * TT + t0 + r) * Hh))[tid];
    }
    __syncthreads();
    const int i0 = tid, i1 = tid + 256;
    const float4* w0p = (const float4*)(Wv + (size_t)i0 * Hh);
    const float4* w1p = (const float4*)(Wv + (size_t)i1 * Hh);
    float acc0[4] = {0.f, 0.f, 0.f, 0.f}, acc1[4] = {0.f, 0.f, 0.f, 0.f};
    for (int j = 0; j < Hh / 4; ++j) {
        float4 w0 = w0p[j], w1 = w1p[j];
#pragma unroll
        for (int r = 0; r < 4; ++r) {
            float4 e = ((const float4*)esh[r])[j];
            acc0[r] += w0.x * e.x + w0.y * e.y + w0.z * e.z + w0.w * e.w;
            acc1[r] += w1.x * e.x + w1.y * e.y + w1.z * e.z + w1.w * e.w;
        }
    }
    float b0 = b[i0], b1 = b[i1];
#pragma unroll
    for (int r = 0; r < 4; ++r) {
        P[((size_t)c * TT + t0 + r) * Hh + i0] = acc0[r] + b0;
        P[((size_t)c * TT + t0 + r) * Hh + i1] = acc1[r] + b1;
    }
}

// ---- sequential RNN chains, int8. grid 2, 512 thr (8 waves, 2/SIMD).
// Thread r owns FULL row r: W = 32 uint4 i8 = 128 VGPRs, register-resident.
// h as i8[512] in LDS, read as 32 wave-uniform b128 broadcasts. 1 barrier/step.
__global__ void __launch_bounds__(512, 2) k_chain(
    const uint4* __restrict__ Wq8, const float* __restrict__ sWf,
    const float* __restrict__ P, const float* __restrict__ eh0,
    const float* __restrict__ dh0, float* __restrict__ h_seq,
    float* __restrict__ Hd) {
    const int c = blockIdx.x, r = threadIdx.x;
    __shared__ __align__(16) char hq8[2][Hh];

    uint4 wq[32];
#pragma unroll
    for (int u = 0; u < 32; ++u) wq[u] = Wq8[(size_t)(c * 32 + u) * 512 + r];
    const float frow = sWf[c * 512 + r];

    {
        float hv = (c ? dh0 : eh0)[r];
        float qf = fminf(fmaxf(rintf(hv * HSCALE), -127.f), 127.f);
        hq8[0][r] = (char)(int)qf;
    }
    __syncthreads();

    const float* Pc = P + (size_t)c * TT * Hh;
    float pv = Pc[r];

    for (int step = 0; step < 256; ++step) {
        const uint4* hp = (const uint4*)hq8[step & 1];
        int acc0 = 0, acc1 = 0, acc2 = 0, acc3 = 0;
#pragma unroll
        for (int u = 0; u < 32; ++u) {
            uint4 hv = hp[u];
            uint4 wv = wq[u];
            acc0 = dot4i8((int)wv.x, (int)hv.x, acc0);
            acc1 = dot4i8((int)wv.y, (int)hv.y, acc1);
            acc2 = dot4i8((int)wv.z, (int)hv.z, acc2);
            acc3 = dot4i8((int)wv.w, (int)hv.w, acc3);
        }
        int s = (acc0 + acc1) + (acc2 + acc3);
        float pre = (float)s * frow + pv;
        float hnew = tanh_fast(pre);
        if (step < 255) pv = Pc[(size_t)(step + 1) * Hh + r];
        float qf = fminf(fmaxf(rintf(hnew * HSCALE), -127.f), 127.f);
        hq8[(step + 1) & 1][r] = (char)(int)qf;
        if (c == 0)
            h_seq[(size_t)(step + 1) * Hh + r] = hnew;
        else if (step < 255)
            Hd[(size_t)(step + 1) * Hh + r] = hnew;
        __syncthreads();
    }
}

// ---- attention scores + context for all t. grid 256, 256 thr. Writes CH=[c|h].
__global__ void __launch_bounds__(256) k_scores(const float* __restrict__ h_seq,
                                                const float* __restrict__ Hd,
                                                float* __restrict__ CH) {
    const int t = blockIdx.x, tid = threadIdx.x;
    __shared__ float h[Hh];
    __shared__ float w[257];
    __shared__ float red[4];
    ((float2*)h)[tid] = ((const float2*)(Hd + (size_t)t * Hh))[tid];
    __syncthreads();
    float sc0, sc1 = -3.0e38f;
    {
        const float4* row = (const float4*)(h_seq + (size_t)tid * Hh);
        float a = 0.f;
        for (int j = 0; j < Hh / 4; ++j) {
            float4 v = row[j];
            a += v.x * h[4 * j] + v.y * h[4 * j + 1] + v.z * h[4 * j + 2] +
                 v.w * h[4 * j + 3];
        }
        sc0 = a;
    }
    if (tid == 0) {
        const float4* row = (const float4*)(h_seq + (size_t)256 * Hh);
        float a = 0.f;
        for (int j = 0; j < Hh / 4; ++j) {
            float4 v = row[j];
            a += v.x * h[4 * j] + v.y * h[4 * j + 1] + v.z * h[4 * j + 2] +
                 v.w * h[4 * j + 3];
        }
        sc1 = a;
    }
    float m = block_max(fmaxf(sc0, sc1), red);
    float e0 = expf(sc0 - m);
    float e1 = (tid == 0) ? expf(sc1 - m) : 0.f;
    float tot = block_sum(e0 + e1, red);
    float inv = 1.f / tot;
    w[tid] = e0 * inv;
    if (tid == 0) w[256] = e1 * inv;
    __syncthreads();
    float* chrow = CH + (size_t)t * (2 * Hh);
#pragma unroll
    for (int r = 0; r < 2; ++r) {
        int j = tid + r * 256;
        float a = 0.f;
        for (int s = 0; s < 257; ++s) a += w[s] * h_seq[(size_t)s * Hh + j];
        chrow[j] = a;
    }
    ((float2*)(chrow + Hh))[tid] = ((const float2*)h)[tid];
}

// ---- Z = tanh(CH @ tnhW^T + b) as f16. grid 64, 256 thr, 4 t per block.
__global__ void __launch_bounds__(256) k_zgemm(const float* __restrict__ CH,
                                               const float* __restrict__ tnhW,
                                               const float* __restrict__ tnhb,
                                               f16* __restrict__ Zh) {
    const int t0 = blockIdx.x * 4, tid = threadIdx.x;
    __shared__ __align__(16) float chs[4][2 * Hh];
#pragma unroll
    for (int r = 0; r < 4; ++r) {
        ((float4*)chs[r])[tid] = ((const float4*)(CH + (size_t)(t0 + r) * 2 * Hh))[tid];
    }
    __syncthreads();
    const int i0 = tid, i1 = tid + 256;
    const float4* w0p = (const float4*)(tnhW + (size_t)i0 * 2 * Hh);
    const float4* w1p = (const float4*)(tnhW + (size_t)i1 * 2 * Hh);
    float acc0[4] = {0.f, 0.f, 0.f, 0.f}, acc1[4] = {0.f, 0.f, 0.f, 0.f};
    for (int j = 0; j < 2 * Hh / 4; ++j) {
        float4 w0 = w0p[j], w1 = w1p[j];
#pragma unroll
        for (int r = 0; r < 4; ++r) {
            float4 e = ((const float4*)chs[r])[j];
            acc0[r] += w0.x * e.x + w0.y * e.y + w0.z * e.z + w0.w * e.w;
            acc1[r] += w1.x * e.x + w1.y * e.y + w1.z * e.z + w1.w * e.w;
        }
    }
    float b0 = tnhb[i0], b1 = tnhb[i1];
#pragma unroll
    for (int r = 0; r < 4; ++r) {
        Zh[(size_t)(t0 + r) * Hh + i0] = (f16)tanhf(acc0[r] + b0);
        Zh[(size_t)(t0 + r) * Hh + i1] = (f16)tanhf(acc1[r] + b1);
    }
}

// ---- logits via f16 MFMA + fused exp-sum. grid 500 (64 vocab rows), 256 thr.
__global__ void __launch_bounds__(256) k_logits(const f16* __restrict__ Zh,
                                                const float* __restrict__ outW,
                                                const int* __restrict__ tgt,
                                                float* __restrict__ denom,
                                                float* __restrict__ ltgt) {
    const int v0 = blockIdx.x * 64, tid = threadIdx.x;
    const int w = tid >> 6, l = tid & 63;
    const int l15 = l & 15, l4 = l >> 4;
    __shared__ __align__(16) f16 Wt[64][136];
    __shared__ __align__(16) f16 Zt[256][136];
    __shared__ float tsum[4][256];
    __shared__ int tgs[256];
    if (tid < 256) tgs[tid] = tgt[tid];

    f32x4 acc[16];
#pragma unroll
    for (int tt = 0; tt < 16; ++tt) acc[tt] = (f32x4){0.f, 0.f, 0.f, 0.f};

    for (int kc = 0; kc < 4; ++kc) {
        const int k0 = kc * 128;
#pragma unroll
        for (int p = 0; p < 8; ++p) {
            int g = p * 256 + tid;
            int row = g >> 5, f4 = g & 31;
            float4 v = *((const float4*)(outW + (size_t)(v0 + row) * Hh + k0 + f4 * 4));
            f16x2 lo = {(f16)v.x, (f16)v.y};
            f16x2 hi = {(f16)v.z, (f16)v.w};
            uint2 u;
            u.x = __builtin_bit_cast(unsigned, lo);
            u.y = __builtin_bit_cast(unsigned, hi);
            *((uint2*)&Wt[row][f4 * 4]) = u;
        }
#pragma unroll
        for (int p = 0; p < 16; ++p) {
            int g = p * 256 + tid;
            int row = g >> 4, u = g & 15;
            *((uint4*)&Zt[row][u * 8]) =
                *((const uint4*)(Zh + (size_t)row * Hh + k0 + u * 8));
        }
        __syncthreads();
        half8 a[4];
#pragma unroll
        for (int ks = 0; ks < 4; ++ks)
            a[ks] = *((const half8*)&Wt[w * 16 + l15][ks * 32 + l4 * 8]);
#pragma unroll
        for (int tt = 0; tt < 16; ++tt) {
#pragma unroll
            for (int ks = 0; ks < 4; ++ks) {
                half8 b = *((const half8*)&Zt[tt * 16 + l15][ks * 32 + l4 * 8]);
                acc[tt] = __builtin_amdgcn_mfma_f32_16x16x32_f16(a[ks], b, acc[tt],
                                                                 0, 0, 0);
            }
        }
        __syncthreads();
    }
    const int vbase = v0 + w * 16 + l4 * 4;
#pragma unroll
    for (int tt = 0; tt < 16; ++tt) {
        float e = __expf(acc[tt][0]) + __expf(acc[tt][1]) + __expf(acc[tt][2]) +
                  __expf(acc[tt][3]);
        e += __shfl_xor(e, 16);
        e += __shfl_xor(e, 32);
        if (l4 == 0) tsum[w][tt * 16 + l15] = e;
        int tglob = tt * 16 + l15;
        int rel = tgs[tglob] - vbase;
        if (rel >= 0 && rel < 4) {
            float val = (rel == 0) ? acc[tt][0]
                        : (rel == 1) ? acc[tt][1]
                        : (rel == 2) ? acc[tt][2]
                                     : acc[tt][3];
            ltgt[tglob] = val;
        }
    }
    __syncthreads();
    if (tid < 256) {
        float s = tsum[0][tid] + tsum[1][tid] + tsum[2][tid] + tsum[3][tid];
        atomicAdd(&denom[tid], s);
    }
}

// ---- final: mean over t of log(denom)-ltgt. grid 1, 256 thr
__global__ void k_final(const float* __restrict__ denom, const float* __restrict__ ltgt,
                        float* __restrict__ out) {
    const int t = threadIdx.x;
    float nll = logf(denom[t]) - ltgt[t];
    __shared__ float red[4];
    float v = nll;
#pragma unroll
    for (int o = 1; o < 64; o <<= 1) v += __shfl_xor(v, o);
    if ((t & 63) == 0) red[t >> 6] = v;
    __syncthreads();
    if (t == 0) out[0] = (red[0] + red[1] + red[2] + red[3]) * (1.f / 256.f);
}

extern "C" void kernel_launch(void* const* d_in, const int* in_sizes, int n_in,
                              void* d_out, int out_size, void* d_ws, size_t ws_size,
                              hipStream_t stream) {
    (void)in_sizes; (void)n_in; (void)out_size; (void)ws_size;
    const int* src = (const int*)d_in[0];
    const int* tgt = (const int*)d_in[1];
    const float* enc_emb = (const float*)d_in[2];
    const float* enc_h0 = (const float*)d_in[3];
    const float* enc_Whi = (const float*)d_in[4];
    const float* enc_Whh = (const float*)d_in[5];
    const float* enc_b = (const float*)d_in[6];
    const float* dec_emb = (const float*)d_in[7];
    const float* dec_h0 = (const float*)d_in[8];
    const float* dec_Whi = (const float*)d_in[9];
    const float* dec_Whh = (const float*)d_in[10];
    const float* dec_b = (const float*)d_in[11];
    const float* tnhW = (const float*)d_in[12];
    const float* tnhb = (const float*)d_in[13];
    const float* outW = (const float*)d_in[14];
    float* out = (float*)d_out;
    char* ws = (char*)d_ws;

    float* denom = (float*)ws;           // 256 f32
    float* ltgt = (float*)(ws + 1024);   // 256 f32
    size_t off = 4096;
    float* emb = (float*)(ws + off);    off += (size_t)2 * TT * Hh * 4;   // 1MB
    float* P = (float*)(ws + off);      off += (size_t)2 * TT * Hh * 4;   // 1MB
    float* h_seq = (float*)(ws + off);  off += (size_t)264 * Hh * 4;      // 528KB
    float* Hd = (float*)(ws + off);     off += (size_t)256 * Hh * 4;      // 512KB
    float* CH = (float*)(ws + off);     off += (size_t)TT * 2 * Hh * 4;   // 1MB
    f16* Zh = (f16*)(ws + off);         off += (size_t)TT * Hh * 2;       // 256KB
    uint4* Wq8 = (uint4*)(ws + off);    off += (size_t)2 * Hh * Hh;       // 512KB
    float* sWf = (float*)(ws + off);    off += (size_t)2 * Hh * 4;        // 4KB

    hipMemsetAsync(ws, 0, 4096, stream);  // denom + ltgt
    k_cvt<<<1024, 128, 0, stream>>>(enc_Whh, dec_Whh, (unsigned int*)Wq8, sWf);
    k_emb<<<512, 256, 0, stream>>>(src, tgt, enc_emb, dec_emb, emb);
    k_init<<<2, 256, 0, stream>>>(enc_h0, dec_h0, h_seq, Hd);
    k_proj<<<dim3(64, 2), 256, 0, stream>>>(emb, enc_Whi, enc_b, dec_Whi, dec_b, P);
    k_chain<<<2, 512, 0, stream>>>(Wq8, sWf, P, enc_h0, dec_h0, h_seq, Hd);
    k_scores<<<256, 256, 0, stream>>>(h_seq, Hd, CH);
    k_zgemm<<<64, 256, 0, stream>>>(CH, tnhW, tnhb, Zh);
    k_logits<<<500, 256, 0, stream>>>(Zh, outW, tgt, denom, ltgt);
    k_final<<<1, 256, 0, stream>>>(denom, ltgt, out);
}

// Round 7
// 332.336 us; speedup vs baseline: 4.8933x; 1.1181x over previous
//
#include <hip/hip_runtime.h>

typedef _Float16 f16;
typedef _Float16 f16x2 __attribute__((ext_vector_type(2)));
typedef _Float16 half8 __attribute__((ext_vector_type(8)));
typedef float f32x4 __attribute__((ext_vector_type(4)));

#define Hh 512
#define TT 256
#define VTOT 32000

#if __has_builtin(__builtin_amdgcn_sdot8)
#define USE_I4 1
#else
#define USE_I4 0
#endif
#define S4H 100.0f      // i4 h quant scale
#define HSCALE 1600.0f  // i8 h quant scale

__device__ inline int dot4i8(int a, int b, int c) {
#if __has_builtin(__builtin_amdgcn_sdot4)
    return __builtin_amdgcn_sdot4(a, b, c, false);
#else
    int s = c;
#pragma unroll
    for (int i = 0; i < 4; ++i)
        s += (int)(signed char)(a >> (8 * i)) * (int)(signed char)(b >> (8 * i));
    return s;
#endif
}

__device__ inline float tanh_fast(float x) {
    float ax = fabsf(x);
    float t = __expf(-2.f * ax);
    float th = (1.f - t) * __builtin_amdgcn_rcpf(1.f + t);
    return copysignf(th, x);
}

__device__ inline float block_sum(float v, float* red) {
#pragma unroll
    for (int o = 1; o < 64; o <<= 1) v += __shfl_xor(v, o);
    if ((threadIdx.x & 63) == 0) red[threadIdx.x >> 6] = v;
    __syncthreads();
    v = red[0] + red[1] + red[2] + red[3];
    __syncthreads();
    return v;
}

__device__ inline float block_max(float v, float* red) {
#pragma unroll
    for (int o = 1; o < 64; o <<= 1) v = fmaxf(v, __shfl_xor(v, o));
    if ((threadIdx.x & 63) == 0) red[threadIdx.x >> 6] = v;
    __syncthreads();
    v = fmaxf(fmaxf(red[0], red[1]), fmaxf(red[2], red[3]));
    __syncthreads();
    return v;
}

// ---- prep: embeddings (blocks 0..511) + h0 init (blocks 512,513). 256 thr
__global__ void __launch_bounds__(256) k_prep(const int* __restrict__ src,
                                              const int* __restrict__ tgt,
                                              const float* __restrict__ encW,
                                              const float* __restrict__ decW,
                                              const float* __restrict__ eh0,
                                              const float* __restrict__ dh0,
                                              float* __restrict__ emb,
                                              float* __restrict__ h_seq,
                                              float* __restrict__ Hd) {
    const int b = blockIdx.x, tid = threadIdx.x;
    if (b >= 512) {
        const int c = b - 512;
        float2 v = ((const float2*)(c ? dh0 : eh0))[tid];
        if (c == 0)
            ((float2*)h_seq)[tid] = v;
        else
            ((float2*)Hd)[tid] = v;
        return;
    }
    const int c = b >> 8, t = b & 255;
    const int idx = c ? tgt[t] : src[t];
    const float* row = (c ? decW : encW) + (size_t)idx * Hh;
    float2 v = ((const float2*)row)[tid];
    __shared__ float red[4];
    float tot = block_sum(v.x * v.x + v.y * v.y, red);
    float inv = 1.f / fmaxf(sqrtf(tot), 1e-12f);
    float* orow = emb + ((size_t)c * TT + t) * Hh;
    float2 o;
    o.x = v.x * inv;
    o.y = v.y * inv;
    ((float2*)orow)[tid] = o;
}

#if USE_I4
// ---- W_hh f32 -> i4 (per-row scale). grid 1024 (c,r), 64 thr; thread t: cols 8t..8t+7
__global__ void __launch_bounds__(64) k_cvt(const float* __restrict__ enc,
                                            const float* __restrict__ dec,
                                            unsigned int* __restrict__ Wq,
                                            float* __restrict__ sWf) {
    const int c = blockIdx.x >> 9, r = blockIdx.x & 511, t = threadIdx.x;
    const float* s = (c ? dec : enc) + (size_t)r * Hh + t * 8;
    float4 v0 = ((const float4*)s)[0];
    float4 v1 = ((const float4*)s)[1];
    float vv[8] = {v0.x, v0.y, v0.z, v0.w, v1.x, v1.y, v1.z, v1.w};
    float m = 0.f;
#pragma unroll
    for (int j = 0; j < 8; ++j) m = fmaxf(m, fabsf(vv[j]));
#pragma unroll
    for (int o = 1; o < 64; o <<= 1) m = fmaxf(m, __shfl_xor(m, o));
    m = fmaxf(m, 1e-30f);
    float qs = 7.f / m;
    unsigned int dw = 0;
#pragma unroll
    for (int j = 0; j < 8; ++j) {
        int q = (int)rintf(vv[j] * qs);
        dw |= ((unsigned int)(q & 0xF)) << (4 * j);
    }
    const int half = t >> 5, u = (t >> 2) & 7, dwi = t & 3;
    Wq[(((size_t)(c * 16 + half * 8 + u) * 512 + r) << 2) + dwi] = dw;
    if (t == 0) sWf[c * 512 + r] = m * (1.f / (7.f * S4H));
}

// ---- RNN chains, i4 x i4 dot8. grid 2, 1024 thr (16 waves, 4/SIMD).
// Thread (r=tid>>1, half=tid&1): 256 cols of row r. W = 8 uint4 (32 VGPR, pinned).
// h i4-packed in LDS (256B/buffer); repack via shfl_down tree. 1 barrier/step.
__global__ void __launch_bounds__(1024, 4) k_chain(
    const uint4* __restrict__ Wq, const float* __restrict__ sWf,
    const float* __restrict__ P, const float* __restrict__ eh0,
    const float* __restrict__ dh0, float* __restrict__ h_seq,
    float* __restrict__ Hd) {
    const int c = blockIdx.x, tid = threadIdx.x;
    const int r = tid >> 1, half = tid & 1;
    __shared__ __align__(16) int hq[2][64];

    uint4 wq[8];
#pragma unroll
    for (int u = 0; u < 8; ++u) wq[u] = Wq[(size_t)(c * 16 + half * 8 + u) * 512 + r];
#pragma unroll
    for (int u = 0; u < 8; ++u)
        asm volatile("" : "+v"(wq[u].x), "+v"(wq[u].y), "+v"(wq[u].z), "+v"(wq[u].w));
    const float frow = sWf[c * 512 + r];
    {
        float hv = (c ? dh0 : eh0)[r];
        int q = (int)rintf(fminf(fmaxf(hv * S4H, -7.f), 7.f));
        int q2 = (q & 0xF) | ((__shfl_down(q, 2) & 0xF) << 4);
        int q4 = (q2 & 0xFF) | ((__shfl_down(q2, 4) & 0xFF) << 8);
        int q8 = (q4 & 0xFFFF) | (__shfl_down(q4, 8) << 16);
        if ((tid & 15) == 0) hq[0][tid >> 4] = q8;
    }
    __syncthreads();

    const float* Pc = P + (size_t)c * TT * Hh;
    float pv = Pc[r];

    for (int step = 0; step < 256; ++step) {
        const uint4* hp = (const uint4*)hq[step & 1];
        int a0 = 0, a1 = 0, a2 = 0, a3 = 0;
#pragma unroll
        for (int u = 0; u < 8; ++u) {
            uint4 hv = hp[half * 8 + u];
            uint4 wv = wq[u];
            a0 = __builtin_amdgcn_sdot8((int)wv.x, (int)hv.x, a0, false);
            a1 = __builtin_amdgcn_sdot8((int)wv.y, (int)hv.y, a1, false);
            a2 = __builtin_amdgcn_sdot8((int)wv.z, (int)hv.z, a2, false);
            a3 = __builtin_amdgcn_sdot8((int)wv.w, (int)hv.w, a3, false);
        }
        float ssum = (float)((a0 + a1) + (a2 + a3));
        ssum += __shfl_xor(ssum, 1);
        float pre = ssum * frow + pv;
        float hnew = tanh_fast(pre);
        if (step < 255) pv = Pc[(size_t)(step + 1) * Hh + r];
        int q = (int)rintf(fminf(fmaxf(hnew * S4H, -7.f), 7.f));
        int q2 = (q & 0xF) | ((__shfl_down(q, 2) & 0xF) << 4);
        int q4 = (q2 & 0xFF) | ((__shfl_down(q2, 4) & 0xFF) << 8);
        int q8 = (q4 & 0xFFFF) | (__shfl_down(q4, 8) << 16);
        if ((tid & 15) == 0) hq[(step + 1) & 1][tid >> 4] = q8;
        if (half == 0) {
            if (c == 0)
                h_seq[(size_t)(step + 1) * Hh + r] = hnew;
            else if (step < 255)
                Hd[(size_t)(step + 1) * Hh + r] = hnew;
        }
        __syncthreads();
    }
}
#else
// ---- W_hh f32 -> i8 (per-row scale). grid 1024 (c,r), 128 thr; thread t: cols 4t..4t+3
__global__ void __launch_bounds__(128) k_cvt(const float* __restrict__ enc,
                                             const float* __restrict__ dec,
                                             unsigned int* __restrict__ Wq,
                                             float* __restrict__ sWf) {
    const int c = blockIdx.x >> 9, r = blockIdx.x & 511, t = threadIdx.x;
    const float* s = (c ? dec : enc) + (size_t)r * Hh + t * 4;
    float4 v = *((const float4*)s);
    float m4 = fmaxf(fmaxf(fabsf(v.x), fabsf(v.y)), fmaxf(fabsf(v.z), fabsf(v.w)));
#pragma unroll
    for (int o = 1; o < 64; o <<= 1) m4 = fmaxf(m4, __shfl_xor(m4, o));
    __shared__ float red[2];
    if ((t & 63) == 0) red[t >> 6] = m4;
    __syncthreads();
    float m = fmaxf(fmaxf(red[0], red[1]), 1e-30f);
    float qs = 127.f / m;
    int q0 = (int)rintf(v.x * qs), q1 = (int)rintf(v.y * qs);
    int q2 = (int)rintf(v.z * qs), q3 = (int)rintf(v.w * qs);
    unsigned int pk = (unsigned int)(q0 & 255) | ((unsigned int)(q1 & 255) << 8) |
                      ((unsigned int)(q2 & 255) << 16) | ((unsigned int)(q3 & 255) << 24);
    const int half = t >> 6, u = (t >> 2) & 15, dwi = t & 3;
    Wq[(((size_t)(c * 32 + half * 16 + u) * 512 + r) << 2) + dwi] = pk;
    if (t == 0) sWf[c * 512 + r] = m * (1.f / (127.f * HSCALE));
}

// ---- RNN chains, i8 dot4 fallback. grid 2, 1024 thr. W = 16 uint4 (64 VGPR, pinned).
__global__ void __launch_bounds__(1024, 4) k_chain(
    const uint4* __restrict__ Wq, const float* __restrict__ sWf,
    const float* __restrict__ P, const float* __restrict__ eh0,
    const float* __restrict__ dh0, float* __restrict__ h_seq,
    float* __restrict__ Hd) {
    const int c = blockIdx.x, tid = threadIdx.x;
    const int r = tid >> 1, half = tid & 1;
    __shared__ __align__(16) int hq[2][128];

    uint4 wq[16];
#pragma unroll
    for (int u = 0; u < 16; ++u) wq[u] = Wq[(size_t)(c * 32 + half * 16 + u) * 512 + r];
#pragma unroll
    for (int u = 0; u < 16; ++u)
        asm volatile("" : "+v"(wq[u].x), "+v"(wq[u].y), "+v"(wq[u].z), "+v"(wq[u].w));
    const float frow = sWf[c * 512 + r];
    {
        float hv = (c ? dh0 : eh0)[r];
        int q = (int)rintf(fminf(fmaxf(hv * HSCALE, -127.f), 127.f));
        int q2 = (q & 0xFF) | ((__shfl_down(q, 2) & 0xFF) << 8);
        int q4 = (q2 & 0xFFFF) | (__shfl_down(q2, 4) << 16);
        if ((tid & 7) == 0) hq[0][tid >> 3] = q4;
    }
    __syncthreads();

    const float* Pc = P + (size_t)c * TT * Hh;
    float pv = Pc[r];

    for (int step = 0; step < 256; ++step) {
        const uint4* hp = (const uint4*)hq[step & 1];
        int a0 = 0, a1 = 0, a2 = 0, a3 = 0;
#pragma unroll
        for (int u = 0; u < 16; ++u) {
            uint4 hv = hp[half * 16 + u];
            uint4 wv = wq[u];
            a0 = dot4i8((int)wv.x, (int)hv.x, a0);
            a1 = dot4i8((int)wv.y, (int)hv.y, a1);
            a2 = dot4i8((int)wv.z, (int)hv.z, a2);
            a3 = dot4i8((int)wv.w, (int)hv.w, a3);
        }
        float ssum = (float)((a0 + a1) + (a2 + a3));
        ssum += __shfl_xor(ssum, 1);
        float pre = ssum * frow + pv;
        float hnew = tanh_fast(pre);
        if (step < 255) pv = Pc[(size_t)(step + 1) * Hh + r];
        int q = (int)rintf(fminf(fmaxf(hnew * HSCALE, -127.f), 127.f));
        int q2 = (q & 0xFF) | ((__shfl_down(q, 2) & 0xFF) << 8);
        int q4 = (q2 & 0xFFFF) | (__shfl_down(q2, 4) << 16);
        if ((tid & 7) == 0) hq[(step + 1) & 1][tid >> 3] = q4;
        if (half == 0) {
            if (c == 0)
                h_seq[(size_t)(step + 1) * Hh + r] = hnew;
            else if (step < 255)
                Hd[(size_t)(step + 1) * Hh + r] = hnew;
        }
        __syncthreads();
    }
}
#endif

// ---- P = emb @ W_hi^T + b. grid (64,2,2), 256 thr, 4 t per block, i-split by z.
__global__ void __launch_bounds__(256) k_proj(const float* __restrict__ emb,
                                              const float* __restrict__ eWhi,
                                              const float* __restrict__ eb,
                                              const float* __restrict__ dWhi,
                                              const float* __restrict__ db,
                                              float* __restrict__ P) {
    const int c = blockIdx.y, t0 = blockIdx.x * 4, tid = threadIdx.x;
    const int i = tid + blockIdx.z * 256;
    const float* Wv = c ? dWhi : eWhi;
    const float* b = c ? db : eb;
    __shared__ __align__(16) float esh[4][Hh];
#pragma unroll
    for (int rr = 0; rr < 4; ++rr) {
        ((float2*)esh[rr])[tid] =
            ((const float2*)(emb + ((size_t)c * TT + t0 + rr) * Hh))[tid];
    }
    __syncthreads();
    const float4* wp = (const float4*)(Wv + (size_t)i * Hh);
    float acc[4] = {0.f, 0.f, 0.f, 0.f};
    for (int j = 0; j < Hh / 4; ++j) {
        float4 w0 = wp[j];
#pragma unroll
        for (int rr = 0; rr < 4; ++rr) {
            float4 e = ((const float4*)esh[rr])[j];
            acc[rr] += w0.x * e.x + w0.y * e.y + w0.z * e.z + w0.w * e.w;
        }
    }
    float b0 = b[i];
#pragma unroll
    for (int rr = 0; rr < 4; ++rr)
        P[((size_t)c * TT + t0 + rr) * Hh + i] = acc[rr] + b0;
}

// ---- attention scores + context for all t. grid 256, 256 thr. Writes CH=[c|h].
__global__ void __launch_bounds__(256) k_scores(const float* __restrict__ h_seq,
                                                const float* __restrict__ Hd,
                                                float* __restrict__ CH) {
    const int t = blockIdx.x, tid = threadIdx.x;
    __shared__ float h[Hh];
    __shared__ float w[257];
    __shared__ float red[4];
    ((float2*)h)[tid] = ((const float2*)(Hd + (size_t)t * Hh))[tid];
    __syncthreads();
    float sc0, sc1 = -3.0e38f;
    {
        const float4* row = (const float4*)(h_seq + (size_t)tid * Hh);
        float a = 0.f;
        for (int j = 0; j < Hh / 4; ++j) {
            float4 v = row[j];
            a += v.x * h[4 * j] + v.y * h[4 * j + 1] + v.z * h[4 * j + 2] +
                 v.w * h[4 * j + 3];
        }
        sc0 = a;
    }
    if (tid == 0) {
        const float4* row = (const float4*)(h_seq + (size_t)256 * Hh);
        float a = 0.f;
        for (int j = 0; j < Hh / 4; ++j) {
            float4 v = row[j];
            a += v.x * h[4 * j] + v.y * h[4 * j + 1] + v.z * h[4 * j + 2] +
                 v.w * h[4 * j + 3];
        }
        sc1 = a;
    }
    float m = block_max(fmaxf(sc0, sc1), red);
    float e0 = expf(sc0 - m);
    float e1 = (tid == 0) ? expf(sc1 - m) : 0.f;
    float tot = block_sum(e0 + e1, red);
    float inv = 1.f / tot;
    w[tid] = e0 * inv;
    if (tid == 0) w[256] = e1 * inv;
    __syncthreads();
    float* chrow = CH + (size_t)t * (2 * Hh);
#pragma unroll
    for (int rr = 0; rr < 2; ++rr) {
        int j = tid + rr * 256;
        float a = 0.f, a2 = 0.f;
        for (int s = 0; s < 256; s += 2) {
            a += w[s] * h_seq[(size_t)s * Hh + j];
            a2 += w[s + 1] * h_seq[(size_t)(s + 1) * Hh + j];
        }
        chrow[j] = a + a2 + w[256] * h_seq[(size_t)256 * Hh + j];
    }
    ((float2*)(chrow + Hh))[tid] = ((const float2*)h)[tid];
}

// ---- Z = tanh(CH @ tnhW^T + b) as f16. grid (64,2), 256 thr, 4 t/block, i-split.
__global__ void __launch_bounds__(256) k_zgemm(const float* __restrict__ CH,
                                               const float* __restrict__ tnhW,
                                               const float* __restrict__ tnhb,
                                               f16* __restrict__ Zh) {
    const int t0 = blockIdx.x * 4, tid = threadIdx.x;
    const int i = tid + blockIdx.y * 256;
    __shared__ __align__(16) float chs[4][2 * Hh];
#pragma unroll
    for (int rr = 0; rr < 4; ++rr) {
        ((float4*)chs[rr])[tid] =
            ((const float4*)(CH + (size_t)(t0 + rr) * 2 * Hh))[tid];
    }
    __syncthreads();
    const float4* wp = (const float4*)(tnhW + (size_t)i * 2 * Hh);
    float acc[4] = {0.f, 0.f, 0.f, 0.f};
    for (int j = 0; j < 2 * Hh / 4; ++j) {
        float4 w0 = wp[j];
#pragma unroll
        for (int rr = 0; rr < 4; ++rr) {
            float4 e = ((const float4*)chs[rr])[j];
            acc[rr] += w0.x * e.x + w0.y * e.y + w0.z * e.z + w0.w * e.w;
        }
    }
    float b0 = tnhb[i];
#pragma unroll
    for (int rr = 0; rr < 4; ++rr)
        Zh[(size_t)(t0 + rr) * Hh + i] = (f16)tanhf(acc[rr] + b0);
}

// ---- logits via f16 MFMA + fused exp-sum. grid 500 (64 vocab rows), 256 thr.
__global__ void __launch_bounds__(256) k_logits(const f16* __restrict__ Zh,
                                                const float* __restrict__ outW,
                                                const int* __restrict__ tgt,
                                                float* __restrict__ denom,
                                                float* __restrict__ ltgt) {
    const int v0 = blockIdx.x * 64, tid = threadIdx.x;
    const int w = tid >> 6, l = tid & 63;
    const int l15 = l & 15, l4 = l >> 4;
    __shared__ __align__(16) f16 Wt[64][136];
    __shared__ __align__(16) f16 Zt[256][136];
    __shared__ float tsum[4][256];
    __shared__ int tgs[256];
    if (tid < 256) tgs[tid] = tgt[tid];

    f32x4 acc[16];
#pragma unroll
    for (int tt = 0; tt < 16; ++tt) acc[tt] = (f32x4){0.f, 0.f, 0.f, 0.f};

    for (int kc = 0; kc < 4; ++kc) {
        const int k0 = kc * 128;
#pragma unroll
        for (int p = 0; p < 8; ++p) {
            int g = p * 256 + tid;
            int row = g >> 5, f4 = g & 31;
            float4 v = *((const float4*)(outW + (size_t)(v0 + row) * Hh + k0 + f4 * 4));
            f16x2 lo = {(f16)v.x, (f16)v.y};
            f16x2 hi = {(f16)v.z, (f16)v.w};
            uint2 u;
            u.x = __builtin_bit_cast(unsigned, lo);
            u.y = __builtin_bit_cast(unsigned, hi);
            *((uint2*)&Wt[row][f4 * 4]) = u;
        }
#pragma unroll
        for (int p = 0; p < 16; ++p) {
            int g = p * 256 + tid;
            int row = g >> 4, u = g & 15;
            *((uint4*)&Zt[row][u * 8]) =
                *((const uint4*)(Zh + (size_t)row * Hh + k0 + u * 8));
        }
        __syncthreads();
        half8 a[4];
#pragma unroll
        for (int ks = 0; ks < 4; ++ks)
            a[ks] = *((const half8*)&Wt[w * 16 + l15][ks * 32 + l4 * 8]);
#pragma unroll
        for (int tt = 0; tt < 16; ++tt) {
#pragma unroll
            for (int ks = 0; ks < 4; ++ks) {
                half8 b = *((const half8*)&Zt[tt * 16 + l15][ks * 32 + l4 * 8]);
                acc[tt] = __builtin_amdgcn_mfma_f32_16x16x32_f16(a[ks], b, acc[tt],
                                                                 0, 0, 0);
            }
        }
        __syncthreads();
    }
    const int vbase = v0 + w * 16 + l4 * 4;
#pragma unroll
    for (int tt = 0; tt < 16; ++tt) {
        float e = __expf(acc[tt][0]) + __expf(acc[tt][1]) + __expf(acc[tt][2]) +
                  __expf(acc[tt][3]);
        e += __shfl_xor(e, 16);
        e += __shfl_xor(e, 32);
        if (l4 == 0) tsum[w][tt * 16 + l15] = e;
        int tglob = tt * 16 + l15;
        int rel = tgs[tglob] - vbase;
        if (rel >= 0 && rel < 4) {
            float val = (rel == 0) ? acc[tt][0]
                        : (rel == 1) ? acc[tt][1]
                        : (rel == 2) ? acc[tt][2]
                                     : acc[tt][3];
            ltgt[tglob] = val;
        }
    }
    __syncthreads();
    if (tid < 256) {
        float s = tsum[0][tid] + tsum[1][tid] + tsum[2][tid] + tsum[3][tid];
        atomicAdd(&denom[tid], s);
    }
}

// ---- final: mean over t of log(denom)-ltgt. grid 1, 256 thr
__global__ void k_final(const float* __restrict__ denom, const float* __restrict__ ltgt,
                        float* __restrict__ out) {
    const int t = threadIdx.x;
    float nll = logf(denom[t]) - ltgt[t];
    __shared__ float red[4];
    float v = nll;
#pragma unroll
    for (int o = 1; o < 64; o <<= 1) v += __shfl_xor(v, o);
    if ((t & 63) == 0) red[t >> 6] = v;
    __syncthreads();
    if (t == 0) out[0] = (red[0] + red[1] + red[2] + red[3]) * (1.f / 256.f);
}

extern "C" void kernel_launch(void* const* d_in, const int* in_sizes, int n_in,
                              void* d_out, int out_size, void* d_ws, size_t ws_size,
                              hipStream_t stream) {
    (void)in_sizes; (void)n_in; (void)out_size; (void)ws_size;
    const int* src = (const int*)d_in[0];
    const int* tgt = (const int*)d_in[1];
    const float* enc_emb = (const float*)d_in[2];
    const float* enc_h0 = (const float*)d_in[3];
    const float* enc_Whi = (const float*)d_in[4];
    const float* enc_Whh = (const float*)d_in[5];
    const float* enc_b = (const float*)d_in[6];
    const float* dec_emb = (const float*)d_in[7];
    const float* dec_h0 = (const float*)d_in[8];
    const float* dec_Whi = (const float*)d_in[9];
    const float* dec_Whh = (const float*)d_in[10];
    const float* dec_b = (const float*)d_in[11];
    const float* tnhW = (const float*)d_in[12];
    const float* tnhb = (const float*)d_in[13];
    const float* outW = (const float*)d_in[14];
    float* out = (float*)d_out;
    char* ws = (char*)d_ws;

    float* denom = (float*)ws;           // 256 f32
    float* ltgt = (float*)(ws + 1024);   // 256 f32
    size_t off = 4096;
    float* emb = (float*)(ws + off);    off += (size_t)2 * TT * Hh * 4;  // 1MB
    float* P = (float*)(ws + off);      off += (size_t)2 * TT * Hh * 4;  // 1MB
    float* h_seq = (float*)(ws + off);  off += (size_t)264 * Hh * 4;     // 528KB
    float* Hd = (float*)(ws + off);     off += (size_t)256 * Hh * 4;     // 512KB
    float* CH = (float*)(ws + off);     off += (size_t)TT * 2 * Hh * 4;  // 1MB
    f16* Zh = (f16*)(ws + off);         off += (size_t)TT * Hh * 2;      // 256KB
    uint4* Wq = (uint4*)(ws + off);     off += (size_t)2 * Hh * Hh;      // <=512KB
    float* sWf = (float*)(ws + off);    off += (size_t)2 * Hh * 4;       // 4KB

    hipMemsetAsync(ws, 0, 4096, stream);  // denom + ltgt
    k_cvt<<<1024, USE_I4 ? 64 : 128, 0, stream>>>(enc_Whh, dec_Whh,
                                                  (unsigned int*)Wq, sWf);
    k_prep<<<514, 256, 0, stream>>>(src, tgt, enc_emb, dec_emb, enc_h0, dec_h0,
                                    emb, h_seq, Hd);
    k_proj<<<dim3(64, 2, 2), 256, 0, stream>>>(emb, enc_Whi, enc_b, dec_Whi, dec_b, P);
    k_chain<<<2, 1024, 0, stream>>>(Wq, sWf, P, enc_h0, dec_h0, h_seq, Hd);
    k_scores<<<256, 256, 0, stream>>>(h_seq, Hd, CH);
    k_zgemm<<<dim3(64, 2), 256, 0, stream>>>(CH, tnhW, tnhb, Zh);
    k_logits<<<500, 256, 0, stream>>>(Zh, outW, tgt, denom, ltgt);
    k_final<<<1, 256, 0, stream>>>(denom, ltgt, out);
}

// Round 8
// 306.525 us; speedup vs baseline: 5.3053x; 1.0842x over previous
//
#include <hip/hip_runtime.h>

typedef _Float16 f16;
typedef _Float16 f16x2 __attribute__((ext_vector_type(2)));
typedef _Float16 half8 __attribute__((ext_vector_type(8)));
typedef float f32x4 __attribute__((ext_vector_type(4)));

#define Hh 512
#define TT 256
#define VTOT 32000
#define S4H 100.0f  // i4 h quant scale

__device__ inline int dot8i4(int a, int b, int c) {
#if __has_builtin(__builtin_amdgcn_sdot8)
    return __builtin_amdgcn_sdot8(a, b, c, false);
#else
    int s = c;
#pragma unroll
    for (int i = 0; i < 8; ++i)
        s += ((a << (28 - 4 * i)) >> 28) * ((b << (28 - 4 * i)) >> 28);
    return s;
#endif
}

__device__ inline float tanh_fast(float x) {
    float ax = fabsf(x);
    float t = __expf(-2.f * ax);
    float th = (1.f - t) * __builtin_amdgcn_rcpf(1.f + t);
    return copysignf(th, x);
}

__device__ inline float block_sum(float v, float* red) {
#pragma unroll
    for (int o = 1; o < 64; o <<= 1) v += __shfl_xor(v, o);
    if ((threadIdx.x & 63) == 0) red[threadIdx.x >> 6] = v;
    __syncthreads();
    v = red[0] + red[1] + red[2] + red[3];
    __syncthreads();
    return v;
}

__device__ inline float block_max(float v, float* red) {
#pragma unroll
    for (int o = 1; o < 64; o <<= 1) v = fmaxf(v, __shfl_xor(v, o));
    if ((threadIdx.x & 63) == 0) red[threadIdx.x >> 6] = v;
    __syncthreads();
    v = fmaxf(fmaxf(red[0], red[1]), fmaxf(red[2], red[3]));
    __syncthreads();
    return v;
}

// ---- prep: emb gather+norm (b<512), h0 init (512,513), W_hh->i4 cvt (514..769).
// 256 thr.
__global__ void __launch_bounds__(256) k_prep(
    const int* __restrict__ src, const int* __restrict__ tgt,
    const float* __restrict__ encW, const float* __restrict__ decW,
    const float* __restrict__ eh0, const float* __restrict__ dh0,
    const float* __restrict__ encWhh, const float* __restrict__ decWhh,
    float* __restrict__ emb, float* __restrict__ h_seq, float* __restrict__ Hd,
    unsigned int* __restrict__ Wq, float* __restrict__ sWf) {
    const int b = blockIdx.x, tid = threadIdx.x;
    if (b >= 514) {  // W cvt: 4 rows per block, one row per wave
        const int bc = b - 514;
        const int R = bc * 4 + (tid >> 6);  // [0,1024)
        const int c = R >> 9, r = R & 511, j = tid & 63;
        const float* s = (c ? decWhh : encWhh) + (size_t)r * Hh + j * 8;
        float4 v0 = ((const float4*)s)[0];
        float4 v1 = ((const float4*)s)[1];
        float vv[8] = {v0.x, v0.y, v0.z, v0.w, v1.x, v1.y, v1.z, v1.w};
        float m = 0.f;
#pragma unroll
        for (int k = 0; k < 8; ++k) m = fmaxf(m, fabsf(vv[k]));
#pragma unroll
        for (int o = 1; o < 64; o <<= 1) m = fmaxf(m, __shfl_xor(m, o));
        m = fmaxf(m, 1e-30f);
        float qs = 7.f / m;
        unsigned int dw = 0;
#pragma unroll
        for (int k = 0; k < 8; ++k) {
            int q = (int)rintf(vv[k] * qs);
            dw |= ((unsigned int)(q & 0xF)) << (4 * k);
        }
        const int r01 = r & 1, th = r >> 1, u = j >> 2, dwi = j & 3;
        Wq[((((size_t)(c * 2 + r01) * 16 + u) * 256 + th) << 2) + dwi] = dw;
        if (j == 0) sWf[c * 512 + r] = m * (1.f / (7.f * S4H));
        return;
    }
    if (b >= 512) {  // h0 init
        const int c = b - 512;
        float2 v = ((const float2*)(c ? dh0 : eh0))[tid];
        if (c == 0)
            ((float2*)h_seq)[tid] = v;
        else
            ((float2*)Hd)[tid] = v;
        return;
    }
    const int c = b >> 8, t = b & 255;
    const int idx = c ? tgt[t] : src[t];
    const float* row = (c ? decW : encW) + (size_t)idx * Hh;
    float2 v = ((const float2*)row)[tid];
    __shared__ float red[4];
    float tot = block_sum(v.x * v.x + v.y * v.y, red);
    float inv = 1.f / fmaxf(sqrtf(tot), 1e-12f);
    float* orow = emb + ((size_t)c * TT + t) * Hh;
    float2 o;
    o.x = v.x * inv;
    o.y = v.y * inv;
    ((float2*)orow)[tid] = o;
}

// ---- P = emb @ W_hi^T + b. grid (64,2,2), 256 thr, 4 t per block, i-split by z.
__global__ void __launch_bounds__(256) k_proj(const float* __restrict__ emb,
                                              const float* __restrict__ eWhi,
                                              const float* __restrict__ eb,
                                              const float* __restrict__ dWhi,
                                              const float* __restrict__ db,
                                              float* __restrict__ P) {
    const int c = blockIdx.y, t0 = blockIdx.x * 4, tid = threadIdx.x;
    const int i = tid + blockIdx.z * 256;
    const float* Wv = c ? dWhi : eWhi;
    const float* b = c ? db : eb;
    __shared__ __align__(16) float esh[4][Hh];
#pragma unroll
    for (int rr = 0; rr < 4; ++rr) {
        ((float2*)esh[rr])[tid] =
            ((const float2*)(emb + ((size_t)c * TT + t0 + rr) * Hh))[tid];
    }
    __syncthreads();
    const float4* wp = (const float4*)(Wv + (size_t)i * Hh);
    float acc[4] = {0.f, 0.f, 0.f, 0.f};
    for (int j = 0; j < Hh / 4; ++j) {
        float4 w0 = wp[j];
#pragma unroll
        for (int rr = 0; rr < 4; ++rr) {
            float4 e = ((const float4*)esh[rr])[j];
            acc[rr] += w0.x * e.x + w0.y * e.y + w0.z * e.z + w0.w * e.w;
        }
    }
    float b0 = b[i];
#pragma unroll
    for (int rr = 0; rr < 4; ++rr)
        P[((size_t)c * TT + t0 + rr) * Hh + i] = acc[rr] + b0;
}

// ---- RNN chains, i4 dot8. grid 2, 256 thr (4 waves, 1/SIMD).
// Thread t owns rows 2t,2t+1 (full 512 cols): W = 32 uint4 = 128 VGPR resident.
// h i4-packed (256B) in LDS; 16 wave-uniform b128 reads/thread/step.
// lgkm-only barrier (global stores float free). 1 barrier/step.
__global__ void __launch_bounds__(256)
    __attribute__((amdgpu_waves_per_eu(1, 1))) k_chain(
        const uint4* __restrict__ Wq, const float* __restrict__ sWf,
        const float* __restrict__ P, const float* __restrict__ eh0,
        const float* __restrict__ dh0, float* __restrict__ h_seq,
        float* __restrict__ Hd) {
    const int c = blockIdx.x, t = threadIdx.x;
    __shared__ __align__(16) int hq[2][64];

    uint4 wq0[16], wq1[16];
#pragma unroll
    for (int u = 0; u < 16; ++u)
        wq0[u] = Wq[((size_t)(c * 2 + 0) * 16 + u) * 256 + t];
#pragma unroll
    for (int u = 0; u < 16; ++u)
        wq1[u] = Wq[((size_t)(c * 2 + 1) * 16 + u) * 256 + t];
#pragma unroll
    for (int u = 0; u < 16; ++u) {
        asm volatile("" : "+v"(wq0[u].x), "+v"(wq0[u].y), "+v"(wq0[u].z),
                          "+v"(wq0[u].w));
        asm volatile("" : "+v"(wq1[u].x), "+v"(wq1[u].y), "+v"(wq1[u].z),
                          "+v"(wq1[u].w));
    }
    float2 frow = *((const float2*)&sWf[c * 512 + 2 * t]);

    {
        const float* h0p = c ? dh0 : eh0;
        float2 h0v = *((const float2*)&h0p[2 * t]);
        int q0 = (int)rintf(fminf(fmaxf(h0v.x * S4H, -7.f), 7.f));
        int q1 = (int)rintf(fminf(fmaxf(h0v.y * S4H, -7.f), 7.f));
        int by = (q0 & 0xF) | ((q1 & 0xF) << 4);
        int b2 = by | (__shfl_down(by, 1) << 8);
        int d = b2 | (__shfl_down(b2, 2) << 16);
        if ((t & 3) == 0) hq[0][t >> 2] = d;
    }
    __syncthreads();

    const float* Pc = P + (size_t)c * TT * Hh;
    float2 pv = *((const float2*)&Pc[2 * t]);

    for (int step = 0; step < 256; ++step) {
        float2 pvn;
        if (step < 255) pvn = *((const float2*)&Pc[(size_t)(step + 1) * Hh + 2 * t]);
        const uint4* hp = (const uint4*)hq[step & 1];
        int a0 = 0, a1 = 0;
#pragma unroll
        for (int u = 0; u < 16; ++u) {
            uint4 hv = hp[u];
            uint4 w0 = wq0[u], w1 = wq1[u];
            a0 = dot8i4((int)w0.x, (int)hv.x, a0);
            a0 = dot8i4((int)w0.y, (int)hv.y, a0);
            a0 = dot8i4((int)w0.z, (int)hv.z, a0);
            a0 = dot8i4((int)w0.w, (int)hv.w, a0);
            a1 = dot8i4((int)w1.x, (int)hv.x, a1);
            a1 = dot8i4((int)w1.y, (int)hv.y, a1);
            a1 = dot8i4((int)w1.z, (int)hv.z, a1);
            a1 = dot8i4((int)w1.w, (int)hv.w, a1);
        }
        float h0n = tanh_fast((float)a0 * frow.x + pv.x);
        float h1n = tanh_fast((float)a1 * frow.y + pv.y);
        pv = pvn;
        float2 st;
        st.x = h0n;
        st.y = h1n;
        if (c == 0)
            *((float2*)&h_seq[(size_t)(step + 1) * Hh + 2 * t]) = st;
        else if (step < 255)
            *((float2*)&Hd[(size_t)(step + 1) * Hh + 2 * t]) = st;
        int q0 = (int)rintf(fminf(fmaxf(h0n * S4H, -7.f), 7.f));
        int q1 = (int)rintf(fminf(fmaxf(h1n * S4H, -7.f), 7.f));
        int by = (q0 & 0xF) | ((q1 & 0xF) << 4);
        int b2 = by | (__shfl_down(by, 1) << 8);
        int d = b2 | (__shfl_down(b2, 2) << 16);
        if ((t & 3) == 0) hq[(step + 1) & 1][t >> 2] = d;
        asm volatile("s_waitcnt lgkmcnt(0)\ns_barrier" ::: "memory");
    }
}

// ---- attention scores + context for all t. grid 256, 256 thr. Writes CH=[c|h].
__global__ void __launch_bounds__(256) k_scores(const float* __restrict__ h_seq,
                                                const float* __restrict__ Hd,
                                                float* __restrict__ CH) {
    const int t = blockIdx.x, tid = threadIdx.x;
    __shared__ float h[Hh];
    __shared__ float w[257];
    __shared__ float red[4];
    ((float2*)h)[tid] = ((const float2*)(Hd + (size_t)t * Hh))[tid];
    __syncthreads();
    float sc0, sc1 = -3.0e38f;
    {
        const float4* row = (const float4*)(h_seq + (size_t)tid * Hh);
        float a = 0.f;
        for (int j = 0; j < Hh / 4; ++j) {
            float4 v = row[j];
            a += v.x * h[4 * j] + v.y * h[4 * j + 1] + v.z * h[4 * j + 2] +
                 v.w * h[4 * j + 3];
        }
        sc0 = a;
    }
    if (tid == 0) {
        const float4* row = (const float4*)(h_seq + (size_t)256 * Hh);
        float a = 0.f;
        for (int j = 0; j < Hh / 4; ++j) {
            float4 v = row[j];
            a += v.x * h[4 * j] + v.y * h[4 * j + 1] + v.z * h[4 * j + 2] +
                 v.w * h[4 * j + 3];
        }
        sc1 = a;
    }
    float m = block_max(fmaxf(sc0, sc1), red);
    float e0 = expf(sc0 - m);
    float e1 = (tid == 0) ? expf(sc1 - m) : 0.f;
    float tot = block_sum(e0 + e1, red);
    float inv = 1.f / tot;
    w[tid] = e0 * inv;
    if (tid == 0) w[256] = e1 * inv;
    __syncthreads();
    float* chrow = CH + (size_t)t * (2 * Hh);
#pragma unroll
    for (int rr = 0; rr < 2; ++rr) {
        int j = tid + rr * 256;
        float a = 0.f, a2 = 0.f;
        for (int s = 0; s < 256; s += 2) {
            a += w[s] * h_seq[(size_t)s * Hh + j];
            a2 += w[s + 1] * h_seq[(size_t)(s + 1) * Hh + j];
        }
        chrow[j] = a + a2 + w[256] * h_seq[(size_t)256 * Hh + j];
    }
    ((float2*)(chrow + Hh))[tid] = ((const float2*)h)[tid];
}

// ---- Z = tanh(CH @ tnhW^T + b) as f16. grid (64,2), 256 thr, 4 t/block, i-split.
__global__ void __launch_bounds__(256) k_zgemm(const float* __restrict__ CH,
                                               const float* __restrict__ tnhW,
                                               const float* __restrict__ tnhb,
                                               f16* __restrict__ Zh) {
    const int t0 = blockIdx.x * 4, tid = threadIdx.x;
    const int i = tid + blockIdx.y * 256;
    __shared__ __align__(16) float chs[4][2 * Hh];
#pragma unroll
    for (int rr = 0; rr < 4; ++rr) {
        ((float4*)chs[rr])[tid] =
            ((const float4*)(CH + (size_t)(t0 + rr) * 2 * Hh))[tid];
    }
    __syncthreads();
    const float4* wp = (const float4*)(tnhW + (size_t)i * 2 * Hh);
    float acc[4] = {0.f, 0.f, 0.f, 0.f};
    for (int j = 0; j < 2 * Hh / 4; ++j) {
        float4 w0 = wp[j];
#pragma unroll
        for (int rr = 0; rr < 4; ++rr) {
            float4 e = ((const float4*)chs[rr])[j];
            acc[rr] += w0.x * e.x + w0.y * e.y + w0.z * e.z + w0.w * e.w;
        }
    }
    float b0 = tnhb[i];
#pragma unroll
    for (int rr = 0; rr < 4; ++rr)
        Zh[(size_t)(t0 + rr) * Hh + i] = (f16)tanhf(acc[rr] + b0);
}

// ---- logits via f16 MFMA + fused exp-sum. grid 500 (64 vocab rows), 256 thr.
__global__ void __launch_bounds__(256) k_logits(const f16* __restrict__ Zh,
                                                const float* __restrict__ outW,
                                                const int* __restrict__ tgt,
                                                float* __restrict__ denom,
                                                float* __restrict__ ltgt) {
    const int v0 = blockIdx.x * 64, tid = threadIdx.x;
    const int w = tid >> 6, l = tid & 63;
    const int l15 = l & 15, l4 = l >> 4;
    __shared__ __align__(16) f16 Wt[64][136];
    __shared__ __align__(16) f16 Zt[256][136];
    __shared__ float tsum[4][256];
    __shared__ int tgs[256];
    if (tid < 256) tgs[tid] = tgt[tid];

    f32x4 acc[16];
#pragma unroll
    for (int tt = 0; tt < 16; ++tt) acc[tt] = (f32x4){0.f, 0.f, 0.f, 0.f};

    for (int kc = 0; kc < 4; ++kc) {
        const int k0 = kc * 128;
#pragma unroll
        for (int p = 0; p < 8; ++p) {
            int g = p * 256 + tid;
            int row = g >> 5, f4 = g & 31;
            float4 v = *((const float4*)(outW + (size_t)(v0 + row) * Hh + k0 + f4 * 4));
            f16x2 lo = {(f16)v.x, (f16)v.y};
            f16x2 hi = {(f16)v.z, (f16)v.w};
            uint2 u;
            u.x = __builtin_bit_cast(unsigned, lo);
            u.y = __builtin_bit_cast(unsigned, hi);
            *((uint2*)&Wt[row][f4 * 4]) = u;
        }
#pragma unroll
        for (int p = 0; p < 16; ++p) {
            int g = p * 256 + tid;
            int row = g >> 4, u = g & 15;
            *((uint4*)&Zt[row][u * 8]) =
                *((const uint4*)(Zh + (size_t)row * Hh + k0 + u * 8));
        }
        __syncthreads();
        half8 a[4];
#pragma unroll
        for (int ks = 0; ks < 4; ++ks)
            a[ks] = *((const half8*)&Wt[w * 16 + l15][ks * 32 + l4 * 8]);
#pragma unroll
        for (int tt = 0; tt < 16; ++tt) {
#pragma unroll
            for (int ks = 0; ks < 4; ++ks) {
                half8 b = *((const half8*)&Zt[tt * 16 + l15][ks * 32 + l4 * 8]);
                acc[tt] = __builtin_amdgcn_mfma_f32_16x16x32_f16(a[ks], b, acc[tt],
                                                                 0, 0, 0);
            }
        }
        __syncthreads();
    }
    const int vbase = v0 + w * 16 + l4 * 4;
#pragma unroll
    for (int tt = 0; tt < 16; ++tt) {
        float e = __expf(acc[tt][0]) + __expf(acc[tt][1]) + __expf(acc[tt][2]) +
                  __expf(acc[tt][3]);
        e += __shfl_xor(e, 16);
        e += __shfl_xor(e, 32);
        if (l4 == 0) tsum[w][tt * 16 + l15] = e;
        int tglob = tt * 16 + l15;
        int rel = tgs[tglob] - vbase;
        if (rel >= 0 && rel < 4) {
            float val = (rel == 0) ? acc[tt][0]
                        : (rel == 1) ? acc[tt][1]
                        : (rel == 2) ? acc[tt][2]
                                     : acc[tt][3];
            ltgt[tglob] = val;
        }
    }
    __syncthreads();
    if (tid < 256) {
        float s = tsum[0][tid] + tsum[1][tid] + tsum[2][tid] + tsum[3][tid];
        atomicAdd(&denom[tid], s);
    }
}

// ---- final: mean over t of log(denom)-ltgt. grid 1, 256 thr
__global__ void k_final(const float* __restrict__ denom, const float* __restrict__ ltgt,
                        float* __restrict__ out) {
    const int t = threadIdx.x;
    float nll = logf(denom[t]) - ltgt[t];
    __shared__ float red[4];
    float v = nll;
#pragma unroll
    for (int o = 1; o < 64; o <<= 1) v += __shfl_xor(v, o);
    if ((t & 63) == 0) red[t >> 6] = v;
    __syncthreads();
    if (t == 0) out[0] = (red[0] + red[1] + red[2] + red[3]) * (1.f / 256.f);
}

extern "C" void kernel_launch(void* const* d_in, const int* in_sizes, int n_in,
                              void* d_out, int out_size, void* d_ws, size_t ws_size,
                              hipStream_t stream) {
    (void)in_sizes; (void)n_in; (void)out_size; (void)ws_size;
    const int* src = (const int*)d_in[0];
    const int* tgt = (const int*)d_in[1];
    const float* enc_emb = (const float*)d_in[2];
    const float* enc_h0 = (const float*)d_in[3];
    const float* enc_Whi = (const float*)d_in[4];
    const float* enc_Whh = (const float*)d_in[5];
    const float* enc_b = (const float*)d_in[6];
    const float* dec_emb = (const float*)d_in[7];
    const float* dec_h0 = (const float*)d_in[8];
    const float* dec_Whi = (const float*)d_in[9];
    const float* dec_Whh = (const float*)d_in[10];
    const float* dec_b = (const float*)d_in[11];
    const float* tnhW = (const float*)d_in[12];
    const float* tnhb = (const float*)d_in[13];
    const float* outW = (const float*)d_in[14];
    float* out = (float*)d_out;
    char* ws = (char*)d_ws;

    float* denom = (float*)ws;           // 256 f32
    float* ltgt = (float*)(ws + 1024);   // 256 f32
    size_t off = 4096;
    float* emb = (float*)(ws + off);    off += (size_t)2 * TT * Hh * 4;  // 1MB
    float* P = (float*)(ws + off);      off += (size_t)2 * TT * Hh * 4;  // 1MB
    float* h_seq = (float*)(ws + off);  off += (size_t)264 * Hh * 4;     // 528KB
    float* Hd = (float*)(ws + off);     off += (size_t)256 * Hh * 4;     // 512KB
    float* CH = (float*)(ws + off);     off += (size_t)TT * 2 * Hh * 4;  // 1MB
    f16* Zh = (f16*)(ws + off);         off += (size_t)TT * Hh * 2;      // 256KB
    uint4* Wq = (uint4*)(ws + off);     off += (size_t)2 * Hh * Hh;      // <=512KB
    float* sWf = (float*)(ws + off);    off += (size_t)2 * Hh * 4;       // 4KB

    hipMemsetAsync(ws, 0, 4096, stream);  // denom + ltgt
    k_prep<<<770, 256, 0, stream>>>(src, tgt, enc_emb, dec_emb, enc_h0, dec_h0,
                                    enc_Whh, dec_Whh, emb, h_seq, Hd,
                                    (unsigned int*)Wq, sWf);
    k_proj<<<dim3(64, 2, 2), 256, 0, stream>>>(emb, enc_Whi, enc_b, dec_Whi, dec_b, P);
    k_chain<<<2, 256, 0, stream>>>(Wq, sWf, P, enc_h0, dec_h0, h_seq, Hd);
    k_scores<<<256, 256, 0, stream>>>(h_seq, Hd, CH);
    k_zgemm<<<dim3(64, 2), 256, 0, stream>>>(CH, tnhW, tnhb, Zh);
    k_logits<<<500, 256, 0, stream>>>(Zh, outW, tgt, denom, ltgt);
    k_final<<<1, 256, 0, stream>>>(denom, ltgt, out);
}